// Round 6
// baseline (385.510 us; speedup 1.0000x reference)
//
#include <hip/hip_runtime.h>
#include <stdint.h>

#define HW    3136
#define CH    256
#define NBAT  16
#define RDIM  2304          // CH * 9
#define NPOS  50176         // NBAT * HW
#define EPSV  1e-5f
#define NCOL  1568          // 784 blocks * 2 halves

typedef __bf16 bf16x8 __attribute__((ext_vector_type(8)));
typedef float  f32x4  __attribute__((ext_vector_type(4)));
typedef unsigned int u32x4 __attribute__((ext_vector_type(4)));

__device__ __forceinline__ unsigned short f2bf(float f) {
    union { float f; unsigned int u; } z; z.f = f;
    unsigned int u = z.u;
    u += 0x7FFFu + ((u >> 16) & 1u);     // round-to-nearest-even
    return (unsigned short)(u >> 16);
}

__device__ __forceinline__ unsigned int cvtpk(float lo, float hi) {
    unsigned int r;
    asm("v_cvt_pk_bf16_f32 %0, %1, %2" : "=v"(r) : "v"(lo), "v"(hi));
    return r;
}

__device__ __forceinline__ void gload_lds16(const void* g, void* l) {
    __builtin_amdgcn_global_load_lds(
        (const __attribute__((address_space(1))) unsigned int*)g,
        (__attribute__((address_space(3))) unsigned int*)l,
        16, 0, 0);
}

// ---------------- 1. transpose x [B,C,HW] f32 -> x_t [B,HW,C] bf16 ----------------
__global__ __launch_bounds__(256) void k_transpose(const float* __restrict__ x,
                                                   unsigned short* __restrict__ xt) {
    __shared__ float tile[64][65];
    int hw0 = blockIdx.x * 64;
    int c0  = blockIdx.y * 64;
    int b   = blockIdx.z;
    int tx = threadIdx.x & 63;
    int ty = threadIdx.x >> 6;
    const float* xp = x + ((size_t)(b * CH + c0)) * HW + hw0;
#pragma unroll
    for (int i = 0; i < 16; i++) {
        int c_l = ty + i * 4;
        tile[c_l][tx] = xp[(size_t)c_l * HW + tx];
    }
    __syncthreads();
    unsigned short* op = xt + ((size_t)(b * HW + hw0)) * CH + c0;
#pragma unroll
    for (int i = 0; i < 16; i++) {
        int hw_l = ty + i * 4;
        op[(size_t)hw_l * CH + tx] = f2bf(tile[tx][hw_l]);
    }
}

// ---------------- 2. weight [O,C,3,3] f32 -> W2[o][k*256+c] bf16 ----------------
__global__ __launch_bounds__(256) void k_w2(const float* __restrict__ w,
                                            unsigned short* __restrict__ w2) {
    int idx = blockIdx.x * 256 + threadIdx.x;   // exactly 589824 threads
    int c = idx & 255;
    int k = (idx >> 8) % 9;
    int o = idx / RDIM;
    w2[idx] = f2bf(w[o * RDIM + c * 9 + k]);
}

// ---------------- 3. fused im2col-sample + GEMM + BN partial sums ----------------
// 1-D grid 784; XCD-aware mapping: bid%8 = XCD owns 2 batches -> per-XCD L2
// working set = 2*1.6MB xt + 1.15MB W2 < 4MB. 512 thr = 8 waves, LDS 40KB ->
// 4 blocks/CU. Per K-step (BK=64): async-stage A (W2), bilinear-blend B in
// regs -> swizzled ds_write, 16 MFMA/wave.
#define BK 64
__global__ __launch_bounds__(512, 8) void k_fgemm(const unsigned short* __restrict__ xt,
                                                  const float* __restrict__ off,
                                                  const unsigned short* __restrict__ W2,
                                                  float* __restrict__ y,
                                                  float* __restrict__ psum_s,
                                                  float* __restrict__ psum_q) {
    __shared__ __align__(16) unsigned short lA[256 * BK];  // 32 KB
    __shared__ __align__(16) unsigned short lB[64 * BK];   //  8 KB
    int t    = threadIdx.x;
    int wid  = t >> 6;
    int lane = t & 63;

    int bid  = blockIdx.x;
    int xcd  = bid & 7;
    int j    = bid >> 3;                 // 0..97
    int b    = 2 * xcd + (j >= 49 ? 1 : 0);
    int spat = (j >= 49) ? j - 49 : j;
    int n0   = spat * 64;
    const unsigned short* xb = xt + (size_t)b * HW * CH;

    int m_off = (wid >> 1) * 64;
    int n_off = (wid & 1) * 32;
    int fr = lane & 15;
    int fq = lane >> 4;

    // B-fill role: position bp (0..63), channel-group bcg (8 ch)
    int bp  = t >> 3;
    int bcg = t & 7;
    int hw = n0 + bp;
    int h = hw / 56, w = hw - h * 56;
    unsigned short* lbdst = &lB[bp * BK + ((bcg ^ (bp & 7)) * 8)];

    f32x4 acc[4][2];
#pragma unroll
    for (int m = 0; m < 4; m++)
#pragma unroll
        for (int n = 0; n < 2; n++)
            acc[m][n] = (f32x4){0.f, 0.f, 0.f, 0.f};

    for (int tap = 0; tap < 9; tap++) {
        // per-thread bilinear meta (redundant x8 per position; same-addr loads broadcast)
        int   cidx[4];
        float cwgt[4];
        {
            float offY = off[((size_t)(b * 18 + 2 * tap)) * HW + hw];
            float offX = off[((size_t)(b * 18 + 2 * tap + 1)) * HW + hw];
            float py = (float)(h + tap / 3 - 1) + offY;
            float px = (float)(w + tap % 3 - 1) + offX;
            float y0f = floorf(py), x0f = floorf(px);
            float fy = py - y0f, fx = px - x0f;
            float wy[2] = {1.f - fy, fy};
            float wx[2] = {1.f - fx, fx};
#pragma unroll
            for (int jj = 0; jj < 4; jj++) {
                int dy = jj >> 1, dx = jj & 1;
                float ycf = y0f + (float)dy, xcf = x0f + (float)dx;
                bool v = (ycf >= 0.f) && (ycf <= 55.f) && (xcf >= 0.f) && (xcf <= 55.f);
                int yi = min(max((int)ycf, 0), 55);
                int xi = min(max((int)xcf, 0), 55);
                cidx[jj] = yi * 56 + xi;
                cwgt[jj] = v ? wy[dy] * wx[dx] : 0.f;
            }
        }

#pragma unroll
        for (int kk4 = 0; kk4 < 4; kk4++) {
            int r0 = tap * 256 + kk4 * 64;
            int c0 = kk4 * 64 + bcg * 8;
            // issue corner gathers first (L2-resident after XCD mapping)
            u32x4 cv0 = *(const u32x4*)(xb + (size_t)cidx[0] * CH + c0);
            u32x4 cv1 = *(const u32x4*)(xb + (size_t)cidx[1] * CH + c0);
            u32x4 cv2 = *(const u32x4*)(xb + (size_t)cidx[2] * CH + c0);
            u32x4 cv3 = *(const u32x4*)(xb + (size_t)cidx[3] * CH + c0);
            // async-stage A-tile 256x64 (source-swizzled, linear LDS dest)
#pragma unroll
            for (int i = 0; i < 4; i++) {
                int q = t + 512 * i;
                int row = q >> 3;
                int part = (q & 7) ^ (row & 7);
                gload_lds16(W2 + (size_t)row * RDIM + r0 + part * 8,
                            &lA[(size_t)(wid * 64 + 512 * i) * 8]);
            }
            // bilinear blend -> bf16 pack -> swizzled LDS write
            {
                float al[4] = {0.f, 0.f, 0.f, 0.f};
                float ah[4] = {0.f, 0.f, 0.f, 0.f};
#pragma unroll
                for (int i = 0; i < 4; i++) {
                    float w0 = cwgt[0], w1 = cwgt[1], w2v = cwgt[2], w3 = cwgt[3];
                    al[i] = fmaf(w0, __uint_as_float(cv0[i] << 16),
                            fmaf(w1, __uint_as_float(cv1[i] << 16),
                            fmaf(w2v, __uint_as_float(cv2[i] << 16),
                                 w3 * __uint_as_float(cv3[i] << 16))));
                    ah[i] = fmaf(w0, __uint_as_float(cv0[i] & 0xffff0000u),
                            fmaf(w1, __uint_as_float(cv1[i] & 0xffff0000u),
                            fmaf(w2v, __uint_as_float(cv2[i] & 0xffff0000u),
                                 w3 * __uint_as_float(cv3[i] & 0xffff0000u))));
                }
                u32x4 ov;
#pragma unroll
                for (int i = 0; i < 4; i++) ov[i] = cvtpk(al[i], ah[i]);
                *(u32x4*)lbdst = ov;
            }
            __syncthreads();
            // MFMA cluster
            __builtin_amdgcn_s_setprio(1);
#pragma unroll
            for (int kk = 0; kk < 2; kk++) {
                bf16x8 afr[4], bfr[2];
#pragma unroll
                for (int m = 0; m < 4; m++) {
                    int row = m_off + m * 16 + fr;
                    int slot = (kk * 4 + fq) ^ (row & 7);
                    afr[m] = *(const bf16x8*)&lA[row * BK + slot * 8];
                }
#pragma unroll
                for (int n = 0; n < 2; n++) {
                    int row = n_off + n * 16 + fr;
                    int slot = (kk * 4 + fq) ^ (row & 7);
                    bfr[n] = *(const bf16x8*)&lB[row * BK + slot * 8];
                }
#pragma unroll
                for (int m = 0; m < 4; m++)
#pragma unroll
                    for (int n = 0; n < 2; n++)
                        acc[m][n] = __builtin_amdgcn_mfma_f32_16x16x32_bf16(afr[m], bfr[n], acc[m][n], 0, 0, 0);
            }
            __builtin_amdgcn_s_setprio(0);
            __syncthreads();
        }
    }

    // --- y write (pre-BN conv output) ---
    float* yb = y + (size_t)b * CH * HW;
#pragma unroll
    for (int m = 0; m < 4; m++) {
        int o = m_off + m * 16 + fq * 4;
#pragma unroll
        for (int n = 0; n < 2; n++) {
            int p = n0 + n_off + n * 16 + fr;
#pragma unroll
            for (int jj = 0; jj < 4; jj++)
                yb[(size_t)(o + jj) * HW + p] = acc[m][n][jj];
        }
    }

    // --- BN partial sums: reduce over n and fr within each fq group ---
    int blk2 = (b * 49 + spat) * 2 + (wid & 1);
#pragma unroll
    for (int m = 0; m < 4; m++)
#pragma unroll
        for (int jj = 0; jj < 4; jj++) {
            float s = acc[m][0][jj] + acc[m][1][jj];
            float q = acc[m][0][jj] * acc[m][0][jj] + acc[m][1][jj] * acc[m][1][jj];
#pragma unroll
            for (int msk = 1; msk < 16; msk <<= 1) {
                s += __shfl_xor(s, msk);
                q += __shfl_xor(q, msk);
            }
            if (fr == 0) {
                int o = m_off + m * 16 + fq * 4 + jj;
                psum_s[(size_t)o * NCOL + blk2] = s;
                psum_q[(size_t)o * NCOL + blk2] = q;
            }
        }
}

// ---------------- 4. reduce partials -> scale/shift ----------------
__global__ __launch_bounds__(256) void k_stats2(const float* __restrict__ psum_s,
                                                const float* __restrict__ psum_q,
                                                const float* __restrict__ gamma,
                                                const float* __restrict__ beta,
                                                float* __restrict__ scaleArr,
                                                float* __restrict__ shiftArr) {
    int o = blockIdx.x;
    int t = threadIdx.x;
    float s = 0.f, q = 0.f;
    for (int i = t; i < NCOL; i += 256) {
        s += psum_s[(size_t)o * NCOL + i];
        q += psum_q[(size_t)o * NCOL + i];
    }
    __shared__ float r1[256], r2[256];
    r1[t] = s; r2[t] = q;
    __syncthreads();
    for (int st = 128; st > 0; st >>= 1) {
        if (t < st) { r1[t] += r1[t + st]; r2[t] += r2[t + st]; }
        __syncthreads();
    }
    if (t == 0) {
        float inv = 1.f / (float)NPOS;
        float mean = r1[0] * inv;
        float var  = r2[0] * inv - mean * mean;
        float sc = gamma[o] * rsqrtf(var + EPSV);
        scaleArr[o] = sc;
        shiftArr[o] = beta[o] - mean * sc;
    }
}

// ---------------- 5. normalize + ReLU (in place on d_out) ----------------
__global__ __launch_bounds__(256) void k_norm(float* __restrict__ y,
                                              const float* __restrict__ scaleArr,
                                              const float* __restrict__ shiftArr) {
    const int total4 = NBAT * CH * (HW / 4);
    for (int i = blockIdx.x * 256 + threadIdx.x; i < total4; i += gridDim.x * 256) {
        int o = (i / (HW / 4)) & 255;
        float sc = scaleArr[o], sh = shiftArr[o];
        float4 v = ((const float4*)y)[i];
        float4 r;
        r.x = fmaxf(v.x * sc + sh, 0.f);
        r.y = fmaxf(v.y * sc + sh, 0.f);
        r.z = fmaxf(v.z * sc + sh, 0.f);
        r.w = fmaxf(v.w * sc + sh, 0.f);
        ((float4*)y)[i] = r;
    }
}

extern "C" void kernel_launch(void* const* d_in, const int* in_sizes, int n_in,
                              void* d_out, int out_size, void* d_ws, size_t ws_size,
                              hipStream_t stream) {
    const float* x     = (const float*)d_in[0];
    const float* off   = (const float*)d_in[1];
    const float* wgt   = (const float*)d_in[2];
    const float* gamma = (const float*)d_in[3];
    const float* beta  = (const float*)d_in[4];
    float* out = (float*)d_out;     // pre-BN conv output, normalized in place
    char* ws = (char*)d_ws;

    // workspace layout (min ~30.1 MB)
    unsigned short* W2 = (unsigned short*)(ws + 0);          //  1,179,648 B
    unsigned short* xt = (unsigned short*)(ws + 1179648);    // 25,690,112 B
    float* psum_s      = (float*)(ws + 26869760);            //  1,605,632 B
    float* psum_q      = (float*)(ws + 28475392);            //  1,605,632 B
    float* scaleArr    = (float*)(ws + 30081024);            //      1,024 B
    float* shiftArr    = (float*)(ws + 30082048);            //      1,024 B

    k_transpose<<<dim3(49, 4, 16), 256, 0, stream>>>(x, xt);
    k_w2<<<2304, 256, 0, stream>>>(wgt, W2);
    k_fgemm<<<784, 512, 0, stream>>>(xt, off, W2, out, psum_s, psum_q);
    k_stats2<<<256, 256, 0, stream>>>(psum_s, psum_q, gamma, beta, scaleArr, shiftArr);
    k_norm<<<2048, 256, 0, stream>>>(out, scaleArr, shiftArr);
}

// Round 7
// 167.772 us; speedup vs baseline: 2.2978x; 2.2978x over previous
//
#include <hip/hip_runtime.h>
#include <stdint.h>

#define HW    3136
#define CH    256
#define NBAT  16
#define RDIM  2304          // CH * 9
#define NPOS  50176         // NBAT * HW
#define EPSV  1e-5f
#define NCOL  1568          // 784 blocks * 2 halves

typedef __bf16 bf16x8 __attribute__((ext_vector_type(8)));
typedef float  f32x4  __attribute__((ext_vector_type(4)));
typedef unsigned int u32x4 __attribute__((ext_vector_type(4)));

__device__ __forceinline__ unsigned short f2bf(float f) {
    union { float f; unsigned int u; } z; z.f = f;
    unsigned int u = z.u;
    u += 0x7FFFu + ((u >> 16) & 1u);     // round-to-nearest-even
    return (unsigned short)(u >> 16);
}

__device__ __forceinline__ unsigned int cvtpk(float lo, float hi) {
    unsigned int r;
    asm("v_cvt_pk_bf16_f32 %0, %1, %2" : "=v"(r) : "v"(lo), "v"(hi));
    return r;
}

__device__ __forceinline__ void gload_lds16(const void* g, void* l) {
    __builtin_amdgcn_global_load_lds(
        (const __attribute__((address_space(1))) unsigned int*)g,
        (__attribute__((address_space(3))) unsigned int*)l,
        16, 0, 0);
}

// ---------------- 1. transpose x [B,C,HW] f32 -> x_t [B,HW,C] bf16 ----------------
__global__ __launch_bounds__(256) void k_transpose(const float* __restrict__ x,
                                                   unsigned short* __restrict__ xt) {
    __shared__ float tile[64][65];
    int hw0 = blockIdx.x * 64;
    int c0  = blockIdx.y * 64;
    int b   = blockIdx.z;
    int tx = threadIdx.x & 63;
    int ty = threadIdx.x >> 6;
    const float* xp = x + ((size_t)(b * CH + c0)) * HW + hw0;
#pragma unroll
    for (int i = 0; i < 16; i++) {
        int c_l = ty + i * 4;
        tile[c_l][tx] = xp[(size_t)c_l * HW + tx];
    }
    __syncthreads();
    unsigned short* op = xt + ((size_t)(b * HW + hw0)) * CH + c0;
#pragma unroll
    for (int i = 0; i < 16; i++) {
        int hw_l = ty + i * 4;
        op[(size_t)hw_l * CH + tx] = f2bf(tile[tx][hw_l]);
    }
}

// ---------------- 2. weight [O,C,3,3] f32 -> W2[o][k*256+c] bf16 ----------------
__global__ __launch_bounds__(256) void k_w2(const float* __restrict__ w,
                                            unsigned short* __restrict__ w2) {
    int idx = blockIdx.x * 256 + threadIdx.x;   // exactly 589824 threads
    int c = idx & 255;
    int k = (idx >> 8) % 9;
    int o = idx / RDIM;
    w2[idx] = f2bf(w[o * RDIM + c * 9 + k]);
}

// ---------------- 3. fused im2col-sample + GEMM + BN partial sums ----------------
// 1-D grid 784; XCD-aware mapping: bid%8 = XCD owns 2 batches -> per-XCD L2
// working set = 2*1.6MB xt + 1.15MB W2 < 4MB. 512 thr = 8 waves.
// __launch_bounds__(512,4): <=128 VGPR (NO spill — (512,8) capped at ~64 and
// spilled to scratch: FETCH 624MB, dur 364us in round 6). 2 blocks/CU.
#define BK 64
__global__ __launch_bounds__(512, 4) void k_fgemm(const unsigned short* __restrict__ xt,
                                                  const float* __restrict__ off,
                                                  const unsigned short* __restrict__ W2,
                                                  float* __restrict__ y,
                                                  float* __restrict__ psum_s,
                                                  float* __restrict__ psum_q) {
    __shared__ __align__(16) unsigned short lA[256 * BK];  // 32 KB
    __shared__ __align__(16) unsigned short lB[64 * BK];   //  8 KB
    int t    = threadIdx.x;
    int wid  = t >> 6;
    int lane = t & 63;

    int bid  = blockIdx.x;
    int xcd  = bid & 7;
    int j    = bid >> 3;                 // 0..97
    int b    = 2 * xcd + (j >= 49 ? 1 : 0);
    int spat = (j >= 49) ? j - 49 : j;
    int n0   = spat * 64;
    const unsigned short* xb = xt + (size_t)b * HW * CH;

    int m_off = (wid >> 1) * 64;
    int n_off = (wid & 1) * 32;
    int fr = lane & 15;
    int fq = lane >> 4;

    // B-fill role: position bp (0..63), channel-group bcg (8 ch)
    int bp  = t >> 3;
    int bcg = t & 7;
    int hw = n0 + bp;
    int h = hw / 56, w = hw - h * 56;
    unsigned short* lbdst = &lB[bp * BK + ((bcg ^ (bp & 7)) * 8)];

    f32x4 acc[4][2];
#pragma unroll
    for (int m = 0; m < 4; m++)
#pragma unroll
        for (int n = 0; n < 2; n++)
            acc[m][n] = (f32x4){0.f, 0.f, 0.f, 0.f};

    for (int tap = 0; tap < 9; tap++) {
        // per-thread bilinear meta (redundant x8 per position; same-addr loads broadcast)
        int   cidx[4];
        float cwgt[4];
        {
            float offY = off[((size_t)(b * 18 + 2 * tap)) * HW + hw];
            float offX = off[((size_t)(b * 18 + 2 * tap + 1)) * HW + hw];
            float py = (float)(h + tap / 3 - 1) + offY;
            float px = (float)(w + tap % 3 - 1) + offX;
            float y0f = floorf(py), x0f = floorf(px);
            float fy = py - y0f, fx = px - x0f;
            float wy[2] = {1.f - fy, fy};
            float wx[2] = {1.f - fx, fx};
#pragma unroll
            for (int jj = 0; jj < 4; jj++) {
                int dy = jj >> 1, dx = jj & 1;
                float ycf = y0f + (float)dy, xcf = x0f + (float)dx;
                bool v = (ycf >= 0.f) && (ycf <= 55.f) && (xcf >= 0.f) && (xcf <= 55.f);
                int yi = min(max((int)ycf, 0), 55);
                int xi = min(max((int)xcf, 0), 55);
                cidx[jj] = yi * 56 + xi;
                cwgt[jj] = v ? wy[dy] * wx[dx] : 0.f;
            }
        }

#pragma unroll
        for (int kk4 = 0; kk4 < 4; kk4++) {
            int r0 = tap * 256 + kk4 * 64;
            int c0 = kk4 * 64 + bcg * 8;
            // issue corner gathers first (L2-resident after XCD mapping)
            u32x4 cv0 = *(const u32x4*)(xb + (size_t)cidx[0] * CH + c0);
            u32x4 cv1 = *(const u32x4*)(xb + (size_t)cidx[1] * CH + c0);
            u32x4 cv2 = *(const u32x4*)(xb + (size_t)cidx[2] * CH + c0);
            u32x4 cv3 = *(const u32x4*)(xb + (size_t)cidx[3] * CH + c0);
            // async-stage A-tile 256x64 (source-swizzled, linear LDS dest)
#pragma unroll
            for (int i = 0; i < 4; i++) {
                int q = t + 512 * i;
                int row = q >> 3;
                int part = (q & 7) ^ (row & 7);
                gload_lds16(W2 + (size_t)row * RDIM + r0 + part * 8,
                            &lA[(size_t)(wid * 64 + 512 * i) * 8]);
            }
            // bilinear blend -> bf16 pack -> swizzled LDS write
            {
                float al[4] = {0.f, 0.f, 0.f, 0.f};
                float ah[4] = {0.f, 0.f, 0.f, 0.f};
#pragma unroll
                for (int i = 0; i < 4; i++) {
                    float w0 = cwgt[0], w1 = cwgt[1], w2v = cwgt[2], w3 = cwgt[3];
                    al[i] = fmaf(w0, __uint_as_float(cv0[i] << 16),
                            fmaf(w1, __uint_as_float(cv1[i] << 16),
                            fmaf(w2v, __uint_as_float(cv2[i] << 16),
                                 w3 * __uint_as_float(cv3[i] << 16))));
                    ah[i] = fmaf(w0, __uint_as_float(cv0[i] & 0xffff0000u),
                            fmaf(w1, __uint_as_float(cv1[i] & 0xffff0000u),
                            fmaf(w2v, __uint_as_float(cv2[i] & 0xffff0000u),
                                 w3 * __uint_as_float(cv3[i] & 0xffff0000u))));
                }
                u32x4 ov;
#pragma unroll
                for (int i = 0; i < 4; i++) ov[i] = cvtpk(al[i], ah[i]);
                *(u32x4*)lbdst = ov;
            }
            __syncthreads();
            // MFMA cluster
            __builtin_amdgcn_s_setprio(1);
#pragma unroll
            for (int kk = 0; kk < 2; kk++) {
                bf16x8 afr[4], bfr[2];
#pragma unroll
                for (int m = 0; m < 4; m++) {
                    int row = m_off + m * 16 + fr;
                    int slot = (kk * 4 + fq) ^ (row & 7);
                    afr[m] = *(const bf16x8*)&lA[row * BK + slot * 8];
                }
#pragma unroll
                for (int n = 0; n < 2; n++) {
                    int row = n_off + n * 16 + fr;
                    int slot = (kk * 4 + fq) ^ (row & 7);
                    bfr[n] = *(const bf16x8*)&lB[row * BK + slot * 8];
                }
#pragma unroll
                for (int m = 0; m < 4; m++)
#pragma unroll
                    for (int n = 0; n < 2; n++)
                        acc[m][n] = __builtin_amdgcn_mfma_f32_16x16x32_bf16(afr[m], bfr[n], acc[m][n], 0, 0, 0);
            }
            __builtin_amdgcn_s_setprio(0);
            __syncthreads();
        }
    }

    // --- y write (pre-BN conv output) ---
    float* yb = y + (size_t)b * CH * HW;
#pragma unroll
    for (int m = 0; m < 4; m++) {
        int o = m_off + m * 16 + fq * 4;
#pragma unroll
        for (int n = 0; n < 2; n++) {
            int p = n0 + n_off + n * 16 + fr;
#pragma unroll
            for (int jj = 0; jj < 4; jj++)
                yb[(size_t)(o + jj) * HW + p] = acc[m][n][jj];
        }
    }

    // --- BN partial sums: reduce over n and fr within each fq group ---
    int blk2 = (b * 49 + spat) * 2 + (wid & 1);
#pragma unroll
    for (int m = 0; m < 4; m++)
#pragma unroll
        for (int jj = 0; jj < 4; jj++) {
            float s = acc[m][0][jj] + acc[m][1][jj];
            float q = acc[m][0][jj] * acc[m][0][jj] + acc[m][1][jj] * acc[m][1][jj];
#pragma unroll
            for (int msk = 1; msk < 16; msk <<= 1) {
                s += __shfl_xor(s, msk);
                q += __shfl_xor(q, msk);
            }
            if (fr == 0) {
                int o = m_off + m * 16 + fq * 4 + jj;
                psum_s[(size_t)o * NCOL + blk2] = s;
                psum_q[(size_t)o * NCOL + blk2] = q;
            }
        }
}

// ---------------- 4. reduce partials -> scale/shift ----------------
__global__ __launch_bounds__(256) void k_stats2(const float* __restrict__ psum_s,
                                                const float* __restrict__ psum_q,
                                                const float* __restrict__ gamma,
                                                const float* __restrict__ beta,
                                                float* __restrict__ scaleArr,
                                                float* __restrict__ shiftArr) {
    int o = blockIdx.x;
    int t = threadIdx.x;
    float s = 0.f, q = 0.f;
    for (int i = t; i < NCOL; i += 256) {
        s += psum_s[(size_t)o * NCOL + i];
        q += psum_q[(size_t)o * NCOL + i];
    }
    __shared__ float r1[256], r2[256];
    r1[t] = s; r2[t] = q;
    __syncthreads();
    for (int st = 128; st > 0; st >>= 1) {
        if (t < st) { r1[t] += r1[t + st]; r2[t] += r2[t + st]; }
        __syncthreads();
    }
    if (t == 0) {
        float inv = 1.f / (float)NPOS;
        float mean = r1[0] * inv;
        float var  = r2[0] * inv - mean * mean;
        float sc = gamma[o] * rsqrtf(var + EPSV);
        scaleArr[o] = sc;
        shiftArr[o] = beta[o] - mean * sc;
    }
}

// ---------------- 5. normalize + ReLU (in place on d_out) ----------------
__global__ __launch_bounds__(256) void k_norm(float* __restrict__ y,
                                              const float* __restrict__ scaleArr,
                                              const float* __restrict__ shiftArr) {
    const int total4 = NBAT * CH * (HW / 4);
    for (int i = blockIdx.x * 256 + threadIdx.x; i < total4; i += gridDim.x * 256) {
        int o = (i / (HW / 4)) & 255;
        float sc = scaleArr[o], sh = shiftArr[o];
        float4 v = ((const float4*)y)[i];
        float4 r;
        r.x = fmaxf(v.x * sc + sh, 0.f);
        r.y = fmaxf(v.y * sc + sh, 0.f);
        r.z = fmaxf(v.z * sc + sh, 0.f);
        r.w = fmaxf(v.w * sc + sh, 0.f);
        ((float4*)y)[i] = r;
    }
}

extern "C" void kernel_launch(void* const* d_in, const int* in_sizes, int n_in,
                              void* d_out, int out_size, void* d_ws, size_t ws_size,
                              hipStream_t stream) {
    const float* x     = (const float*)d_in[0];
    const float* off   = (const float*)d_in[1];
    const float* wgt   = (const float*)d_in[2];
    const float* gamma = (const float*)d_in[3];
    const float* beta  = (const float*)d_in[4];
    float* out = (float*)d_out;     // pre-BN conv output, normalized in place
    char* ws = (char*)d_ws;

    // workspace layout (min ~30.1 MB)
    unsigned short* W2 = (unsigned short*)(ws + 0);          //  1,179,648 B
    unsigned short* xt = (unsigned short*)(ws + 1179648);    // 25,690,112 B
    float* psum_s      = (float*)(ws + 26869760);            //  1,605,632 B
    float* psum_q      = (float*)(ws + 28475392);            //  1,605,632 B
    float* scaleArr    = (float*)(ws + 30081024);            //      1,024 B
    float* shiftArr    = (float*)(ws + 30082048);            //      1,024 B

    k_transpose<<<dim3(49, 4, 16), 256, 0, stream>>>(x, xt);
    k_w2<<<2304, 256, 0, stream>>>(wgt, W2);
    k_fgemm<<<784, 512, 0, stream>>>(xt, off, W2, out, psum_s, psum_q);
    k_stats2<<<256, 256, 0, stream>>>(psum_s, psum_q, gamma, beta, scaleArr, shiftArr);
    k_norm<<<2048, 256, 0, stream>>>(out, scaleArr, shiftArr);
}

// Round 9
// 164.030 us; speedup vs baseline: 2.3502x; 1.0228x over previous
//
#include <hip/hip_runtime.h>
#include <stdint.h>

#define HW    3136
#define CH    256
#define NBAT  16
#define RDIM  2304          // CH * 9
#define NPOS  50176         // NBAT * HW
#define EPSV  1e-5f
#define NCOL  1568          // 784 blocks * 2 halves

typedef __bf16 bf16x8 __attribute__((ext_vector_type(8)));
typedef float  f32x4  __attribute__((ext_vector_type(4)));
typedef unsigned int u32x4 __attribute__((ext_vector_type(4)));

__device__ __forceinline__ unsigned short f2bf(float f) {
    union { float f; unsigned int u; } z; z.f = f;
    unsigned int u = z.u;
    u += 0x7FFFu + ((u >> 16) & 1u);     // round-to-nearest-even
    return (unsigned short)(u >> 16);
}

__device__ __forceinline__ unsigned int cvtpk(float lo, float hi) {
    unsigned int r;
    asm("v_cvt_pk_bf16_f32 %0, %1, %2" : "=v"(r) : "v"(lo), "v"(hi));
    return r;
}

__device__ __forceinline__ void gload_lds16(const void* g, void* l) {
    __builtin_amdgcn_global_load_lds(
        (const __attribute__((address_space(1))) unsigned int*)g,
        (__attribute__((address_space(3))) unsigned int*)l,
        16, 0, 0);
}

// ---------------- 1. transpose x [B,C,HW] f32 -> x_t [B,HW,C] bf16 ----------------
__global__ __launch_bounds__(256) void k_transpose(const float* __restrict__ x,
                                                   unsigned short* __restrict__ xt) {
    __shared__ float tile[64][65];
    int hw0 = blockIdx.x * 64;
    int c0  = blockIdx.y * 64;
    int b   = blockIdx.z;
    int tx = threadIdx.x & 63;
    int ty = threadIdx.x >> 6;
    const float* xp = x + ((size_t)(b * CH + c0)) * HW + hw0;
#pragma unroll
    for (int i = 0; i < 16; i++) {
        int c_l = ty + i * 4;
        tile[c_l][tx] = xp[(size_t)c_l * HW + tx];
    }
    __syncthreads();
    unsigned short* op = xt + ((size_t)(b * HW + hw0)) * CH + c0;
#pragma unroll
    for (int i = 0; i < 16; i++) {
        int hw_l = ty + i * 4;
        op[(size_t)hw_l * CH + tx] = f2bf(tile[tx][hw_l]);
    }
}

// ---------------- 2. weight [O,C,3,3] f32 -> W2[o][k*256+c] bf16 ----------------
__global__ __launch_bounds__(256) void k_w2(const float* __restrict__ w,
                                            unsigned short* __restrict__ w2) {
    int idx = blockIdx.x * 256 + threadIdx.x;   // exactly 589824 threads
    int c = idx & 255;
    int k = (idx >> 8) % 9;
    int o = idx / RDIM;
    w2[idx] = f2bf(w[o * RDIM + c * 9 + k]);
}

// ---------------- 3. fused im2col-sample + GEMM + BN partial sums ----------------
// XCD-aware: bid%8 = XCD owns 2 batches (L2-resident x_t; round 7: FETCH 24MB).
// Round 8: double-buffered lA/lB, ONE barrier per K-step; next step's gathers +
// A-stage issued BEFORE the MFMA cluster so L2 latency hides under MFMA.
#define BK 64
__global__ __launch_bounds__(512, 4) void k_fgemm(const unsigned short* __restrict__ xt,
                                                  const float* __restrict__ off,
                                                  const unsigned short* __restrict__ W2,
                                                  float* __restrict__ y,
                                                  float* __restrict__ psum_s,
                                                  float* __restrict__ psum_q) {
    __shared__ __align__(16) unsigned short lA[2][256 * BK];  // 64 KB
    __shared__ __align__(16) unsigned short lB[2][64 * BK];   // 16 KB
    int t    = threadIdx.x;
    int wid  = t >> 6;
    int lane = t & 63;

    int bid  = blockIdx.x;
    int xcd  = bid & 7;
    int j    = bid >> 3;                 // 0..97
    int b    = 2 * xcd + (j >= 49 ? 1 : 0);
    int spat = (j >= 49) ? j - 49 : j;
    int n0   = spat * 64;
    const unsigned short* xb = xt + (size_t)b * HW * CH;

    int m_off = (wid >> 1) * 64;
    int n_off = (wid & 1) * 32;
    int fr = lane & 15;
    int fq = lane >> 4;

    // B-fill role: position bp (0..63), channel-group bcg (8 ch)
    int bp  = t >> 3;
    int bcg = t & 7;
    int hw = n0 + bp;
    int h = hw / 56, w = hw - h * 56;
    int lboff = bp * BK + ((bcg ^ (bp & 7)) * 8);   // swizzled LDS slot

    f32x4 acc[4][2];
#pragma unroll
    for (int m = 0; m < 4; m++)
#pragma unroll
        for (int n = 0; n < 2; n++)
            acc[m][n] = (f32x4){0.f, 0.f, 0.f, 0.f};

    int   cidx0, cidx1, cidx2, cidx3;
    float cwgt0, cwgt1, cwgt2, cwgt3;
    float offYn, offXn;

    // meta from (oy,ox) for tap -> corner idx/wgt
#define META_COMPUTE(TAP, OY, OX)                                              \
    {                                                                          \
        float py = (float)(h + (TAP) / 3 - 1) + (OY);                          \
        float px = (float)(w + (TAP) % 3 - 1) + (OX);                          \
        float y0f = floorf(py), x0f = floorf(px);                              \
        float fy = py - y0f, fx = px - x0f;                                    \
        float wy0 = 1.f - fy, wx0 = 1.f - fx;                                  \
        float ycf0 = y0f, ycf1 = y0f + 1.f, xcf0 = x0f, xcf1 = x0f + 1.f;      \
        bool vy0 = (ycf0 >= 0.f) && (ycf0 <= 55.f);                            \
        bool vy1 = (ycf1 >= 0.f) && (ycf1 <= 55.f);                            \
        bool vx0 = (xcf0 >= 0.f) && (xcf0 <= 55.f);                            \
        bool vx1 = (xcf1 >= 0.f) && (xcf1 <= 55.f);                            \
        int yi0 = min(max((int)ycf0, 0), 55), yi1 = min(max((int)ycf1, 0), 55);\
        int xi0 = min(max((int)xcf0, 0), 55), xi1 = min(max((int)xcf1, 0), 55);\
        cidx0 = yi0 * 56 + xi0; cwgt0 = (vy0 && vx0) ? wy0 * wx0 : 0.f;        \
        cidx1 = yi0 * 56 + xi1; cwgt1 = (vy0 && vx1) ? wy0 * fx : 0.f;         \
        cidx2 = yi1 * 56 + xi0; cwgt2 = (vy1 && vx0) ? fy * wx0 : 0.f;         \
        cidx3 = yi1 * 56 + xi1; cwgt3 = (vy1 && vx1) ? fy * fx : 0.f;          \
    }

#define STAGE_A(S, BUF)                                                        \
    {                                                                          \
        _Pragma("unroll")                                                      \
        for (int i = 0; i < 4; i++) {                                          \
            int q = t + 512 * i;                                               \
            int row = q >> 3;                                                  \
            int part = (q & 7) ^ (row & 7);                                    \
            gload_lds16(W2 + (size_t)row * RDIM + (S) * 64 + part * 8,         \
                        &lA[BUF][(size_t)(wid * 64 + 512 * i) * 8]);           \
        }                                                                      \
    }

#define GATHERS(S)                                                             \
    {                                                                          \
        int c0g = ((S) & 3) * 64 + bcg * 8;                                    \
        nv0 = *(const u32x4*)(xb + (size_t)cidx0 * CH + c0g);                  \
        nv1 = *(const u32x4*)(xb + (size_t)cidx1 * CH + c0g);                  \
        nv2 = *(const u32x4*)(xb + (size_t)cidx2 * CH + c0g);                  \
        nv3 = *(const u32x4*)(xb + (size_t)cidx3 * CH + c0g);                  \
    }

#define BLEND_WRITE(BUF)                                                       \
    {                                                                          \
        float al[4] = {0.f, 0.f, 0.f, 0.f};                                    \
        float ah[4] = {0.f, 0.f, 0.f, 0.f};                                    \
        _Pragma("unroll")                                                      \
        for (int i = 0; i < 4; i++) {                                          \
            al[i] = fmaf(cwgt0, __uint_as_float(nv0[i] << 16),                 \
                    fmaf(cwgt1, __uint_as_float(nv1[i] << 16),                 \
                    fmaf(cwgt2, __uint_as_float(nv2[i] << 16),                 \
                         cwgt3 * __uint_as_float(nv3[i] << 16))));             \
            ah[i] = fmaf(cwgt0, __uint_as_float(nv0[i] & 0xffff0000u),         \
                    fmaf(cwgt1, __uint_as_float(nv1[i] & 0xffff0000u),         \
                    fmaf(cwgt2, __uint_as_float(nv2[i] & 0xffff0000u),         \
                         cwgt3 * __uint_as_float(nv3[i] & 0xffff0000u))));     \
        }                                                                      \
        u32x4 ov;                                                              \
        _Pragma("unroll")                                                      \
        for (int i = 0; i < 4; i++) ov[i] = cvtpk(al[i], ah[i]);               \
        *(u32x4*)(&lB[BUF][lboff]) = ov;                                       \
    }

    u32x4 nv0, nv1, nv2, nv3;

    // ---- prologue: prepare step 0 into buffers 0 ----
    {
        float oy = off[((size_t)(b * 18 + 0)) * HW + hw];
        float ox = off[((size_t)(b * 18 + 1)) * HW + hw];
        META_COMPUTE(0, oy, ox);
    }
    GATHERS(0);
    STAGE_A(0, 0);
    offYn = off[((size_t)(b * 18 + 2)) * HW + hw];
    offXn = off[((size_t)(b * 18 + 3)) * HW + hw];
    BLEND_WRITE(0);
    __syncthreads();

    // ---- main loop: one barrier per K-step ----
    for (int s = 0; s < 36; ++s) {
        int cur = s & 1;
        int nxt = cur ^ 1;
        if (s < 35) {
            int s1 = s + 1;
            if ((s1 & 3) == 0) {
                int tap1 = s1 >> 2;
                META_COMPUTE(tap1, offYn, offXn);
                if (tap1 < 8) {
                    offYn = off[((size_t)(b * 18 + 2 * tap1 + 2)) * HW + hw];
                    offXn = off[((size_t)(b * 18 + 2 * tap1 + 3)) * HW + hw];
                }
            }
            GATHERS(s1);
            STAGE_A(s1, nxt);
        }
        // MFMA cluster on buffers[cur] (prefetch latency hides under this)
        __builtin_amdgcn_s_setprio(1);
#pragma unroll
        for (int kk = 0; kk < 2; kk++) {
            bf16x8 afr[4], bfr[2];
#pragma unroll
            for (int m = 0; m < 4; m++) {
                int row = m_off + m * 16 + fr;
                int slot = (kk * 4 + fq) ^ (row & 7);
                afr[m] = *(const bf16x8*)&lA[cur][row * BK + slot * 8];
            }
#pragma unroll
            for (int n = 0; n < 2; n++) {
                int row = n_off + n * 16 + fr;
                int slot = (kk * 4 + fq) ^ (row & 7);
                bfr[n] = *(const bf16x8*)&lB[cur][row * BK + slot * 8];
            }
#pragma unroll
            for (int m = 0; m < 4; m++)
#pragma unroll
                for (int n = 0; n < 2; n++)
                    acc[m][n] = __builtin_amdgcn_mfma_f32_16x16x32_bf16(afr[m], bfr[n], acc[m][n], 0, 0, 0);
        }
        __builtin_amdgcn_s_setprio(0);
        if (s < 35) {
            BLEND_WRITE(nxt);   // compiler inserts vmcnt for nv* before use
        }
        __syncthreads();        // drains STAGE_A vmcnt + ds_write lgkm; one barrier/step
    }

    // --- y write (pre-BN conv output) ---
    float* yb = y + (size_t)b * CH * HW;
#pragma unroll
    for (int m = 0; m < 4; m++) {
        int o = m_off + m * 16 + fq * 4;
#pragma unroll
        for (int n = 0; n < 2; n++) {
            int p = n0 + n_off + n * 16 + fr;
#pragma unroll
            for (int jj = 0; jj < 4; jj++)
                yb[(size_t)(o + jj) * HW + p] = acc[m][n][jj];
        }
    }

    // --- BN partial sums: reduce over n and fr within each fq group ---
    int blk2 = (b * 49 + spat) * 2 + (wid & 1);
#pragma unroll
    for (int m = 0; m < 4; m++)
#pragma unroll
        for (int jj = 0; jj < 4; jj++) {
            float s = acc[m][0][jj] + acc[m][1][jj];
            float q = acc[m][0][jj] * acc[m][0][jj] + acc[m][1][jj] * acc[m][1][jj];
#pragma unroll
            for (int msk = 1; msk < 16; msk <<= 1) {
                s += __shfl_xor(s, msk);
                q += __shfl_xor(q, msk);
            }
            if (fr == 0) {
                int o = m_off + m * 16 + fq * 4 + jj;
                psum_s[(size_t)o * NCOL + blk2] = s;
                psum_q[(size_t)o * NCOL + blk2] = q;
            }
        }
}

// ---------------- 4. reduce partials -> scale/shift ----------------
__global__ __launch_bounds__(256) void k_stats2(const float* __restrict__ psum_s,
                                                const float* __restrict__ psum_q,
                                                const float* __restrict__ gamma,
                                                const float* __restrict__ beta,
                                                float* __restrict__ scaleArr,
                                                float* __restrict__ shiftArr) {
    int o = blockIdx.x;
    int t = threadIdx.x;
    float s = 0.f, q = 0.f;
    for (int i = t; i < NCOL; i += 256) {
        s += psum_s[(size_t)o * NCOL + i];
        q += psum_q[(size_t)o * NCOL + i];
    }
    __shared__ float r1[256], r2[256];
    r1[t] = s; r2[t] = q;
    __syncthreads();
    for (int st = 128; st > 0; st >>= 1) {
        if (t < st) { r1[t] += r1[t + st]; r2[t] += r2[t + st]; }
        __syncthreads();
    }
    if (t == 0) {
        float inv = 1.f / (float)NPOS;
        float mean = r1[0] * inv;
        float var  = r2[0] * inv - mean * mean;
        float sc = gamma[o] * rsqrtf(var + EPSV);
        scaleArr[o] = sc;
        shiftArr[o] = beta[o] - mean * sc;
    }
}

// ---------------- 5. normalize + ReLU (in place on d_out) ----------------
__global__ __launch_bounds__(256) void k_norm(float* __restrict__ y,
                                              const float* __restrict__ scaleArr,
                                              const float* __restrict__ shiftArr) {
    const int total4 = NBAT * CH * (HW / 4);
    for (int i = blockIdx.x * 256 + threadIdx.x; i < total4; i += gridDim.x * 256) {
        int o = (i / (HW / 4)) & 255;
        float sc = scaleArr[o], sh = shiftArr[o];
        float4 v = ((const float4*)y)[i];
        float4 r;
        r.x = fmaxf(v.x * sc + sh, 0.f);
        r.y = fmaxf(v.y * sc + sh, 0.f);
        r.z = fmaxf(v.z * sc + sh, 0.f);
        r.w = fmaxf(v.w * sc + sh, 0.f);
        ((float4*)y)[i] = r;
    }
}

extern "C" void kernel_launch(void* const* d_in, const int* in_sizes, int n_in,
                              void* d_out, int out_size, void* d_ws, size_t ws_size,
                              hipStream_t stream) {
    const float* x     = (const float*)d_in[0];
    const float* off   = (const float*)d_in[1];
    const float* wgt   = (const float*)d_in[2];
    const float* gamma = (const float*)d_in[3];
    const float* beta  = (const float*)d_in[4];
    float* out = (float*)d_out;     // pre-BN conv output, normalized in place
    char* ws = (char*)d_ws;

    // workspace layout (min ~30.1 MB)
    unsigned short* W2 = (unsigned short*)(ws + 0);          //  1,179,648 B
    unsigned short* xt = (unsigned short*)(ws + 1179648);    // 25,690,112 B
    float* psum_s      = (float*)(ws + 26869760);            //  1,605,632 B
    float* psum_q      = (float*)(ws + 28475392);            //  1,605,632 B
    float* scaleArr    = (float*)(ws + 30081024);            //      1,024 B
    float* shiftArr    = (float*)(ws + 30082048);            //      1,024 B

    k_transpose<<<dim3(49, 4, 16), 256, 0, stream>>>(x, xt);
    k_w2<<<2304, 256, 0, stream>>>(wgt, W2);
    k_fgemm<<<784, 512, 0, stream>>>(xt, off, W2, out, psum_s, psum_q);
    k_stats2<<<256, 256, 0, stream>>>(psum_s, psum_q, gamma, beta, scaleArr, shiftArr);
    k_norm<<<2048, 256, 0, stream>>>(out, scaleArr, shiftArr);
}

// Round 13
// 163.512 us; speedup vs baseline: 2.3577x; 1.0032x over previous
//
#include <hip/hip_runtime.h>
#include <stdint.h>

#define HW    3136
#define CH    256
#define NBAT  16
#define RDIM  2304          // CH * 9
#define NPOS  50176         // NBAT * HW
#define EPSV  1e-5f
#define NCOL  1568          // 784 blocks * 2 halves

typedef __bf16 bf16x8 __attribute__((ext_vector_type(8)));
typedef float  f32x4  __attribute__((ext_vector_type(4)));
typedef unsigned int u32x4 __attribute__((ext_vector_type(4)));

__device__ __forceinline__ unsigned short f2bf(float f) {
    union { float f; unsigned int u; } z; z.f = f;
    unsigned int u = z.u;
    u += 0x7FFFu + ((u >> 16) & 1u);     // round-to-nearest-even
    return (unsigned short)(u >> 16);
}

__device__ __forceinline__ unsigned int cvtpk(float lo, float hi) {
    unsigned int r;
    asm("v_cvt_pk_bf16_f32 %0, %1, %2" : "=v"(r) : "v"(lo), "v"(hi));
    return r;
}

__device__ __forceinline__ void gload_lds16(const void* g, void* l) {
    __builtin_amdgcn_global_load_lds(
        (const __attribute__((address_space(1))) unsigned int*)g,
        (__attribute__((address_space(3))) unsigned int*)l,
        16, 0, 0);
}

// ---------------- 1. transpose x [B,C,HW] f32 -> x_t [B,HW,C] bf16 ----------------
__global__ __launch_bounds__(256) void k_transpose(const float* __restrict__ x,
                                                   unsigned short* __restrict__ xt) {
    __shared__ float tile[64][65];
    int hw0 = blockIdx.x * 64;
    int c0  = blockIdx.y * 64;
    int b   = blockIdx.z;
    int tx = threadIdx.x & 63;
    int ty = threadIdx.x >> 6;
    const float* xp = x + ((size_t)(b * CH + c0)) * HW + hw0;
#pragma unroll
    for (int i = 0; i < 16; i++) {
        int c_l = ty + i * 4;
        tile[c_l][tx] = xp[(size_t)c_l * HW + tx];
    }
    __syncthreads();
    unsigned short* op = xt + ((size_t)(b * HW + hw0)) * CH + c0;
#pragma unroll
    for (int i = 0; i < 16; i++) {
        int hw_l = ty + i * 4;
        op[(size_t)hw_l * CH + tx] = f2bf(tile[tx][hw_l]);
    }
}

// ---------------- 2. weight [O,C,3,3] f32 -> W2[o][k*256+c] bf16 ----------------
__global__ __launch_bounds__(256) void k_w2(const float* __restrict__ w,
                                            unsigned short* __restrict__ w2) {
    int idx = blockIdx.x * 256 + threadIdx.x;   // exactly 589824 threads
    int c = idx & 255;
    int k = (idx >> 8) % 9;
    int o = idx / RDIM;
    w2[idx] = f2bf(w[o * RDIM + c * 9 + k]);
}

// ---------------- 3. fused im2col-sample + GEMM + BN partial sums ----------------
// XCD-aware: bid%8 = XCD owns 2 batches (L2-resident x_t; round 7: FETCH 24MB).
// Round 8: double-buffered lA/lB, ONE barrier per K-step; next step's gathers +
// A-stage issued BEFORE the MFMA cluster so L2 latency hides under MFMA.
#define BK 64
__global__ __launch_bounds__(512, 4) void k_fgemm(const unsigned short* __restrict__ xt,
                                                  const float* __restrict__ off,
                                                  const unsigned short* __restrict__ W2,
                                                  float* __restrict__ y,
                                                  float* __restrict__ psum_s,
                                                  float* __restrict__ psum_q) {
    __shared__ __align__(16) unsigned short lA[2][256 * BK];  // 64 KB
    __shared__ __align__(16) unsigned short lB[2][64 * BK];   // 16 KB
    int t    = threadIdx.x;
    int wid  = t >> 6;
    int lane = t & 63;

    int bid  = blockIdx.x;
    int xcd  = bid & 7;
    int j    = bid >> 3;                 // 0..97
    int b    = 2 * xcd + (j >= 49 ? 1 : 0);
    int spat = (j >= 49) ? j - 49 : j;
    int n0   = spat * 64;
    const unsigned short* xb = xt + (size_t)b * HW * CH;

    int m_off = (wid >> 1) * 64;
    int n_off = (wid & 1) * 32;
    int fr = lane & 15;
    int fq = lane >> 4;

    // B-fill role: position bp (0..63), channel-group bcg (8 ch)
    int bp  = t >> 3;
    int bcg = t & 7;
    int hw = n0 + bp;
    int h = hw / 56, w = hw - h * 56;
    int lboff = bp * BK + ((bcg ^ (bp & 7)) * 8);   // swizzled LDS slot

    f32x4 acc[4][2];
#pragma unroll
    for (int m = 0; m < 4; m++)
#pragma unroll
        for (int n = 0; n < 2; n++)
            acc[m][n] = (f32x4){0.f, 0.f, 0.f, 0.f};

    int   cidx0, cidx1, cidx2, cidx3;
    float cwgt0, cwgt1, cwgt2, cwgt3;
    u32x4 nv0, nv1, nv2, nv3;
    float offYn, offXn;

    // meta from (oy,ox) for tap -> corner idx/wgt
#define META_COMPUTE(TAP, OY, OX)                                              \
    {                                                                          \
        float py = (float)(h + (TAP) / 3 - 1) + (OY);                          \
        float px = (float)(w + (TAP) % 3 - 1) + (OX);                          \
        float y0f = floorf(py), x0f = floorf(px);                              \
        float fy = py - y0f, fx = px - x0f;                                    \
        float wy0 = 1.f - fy, wx0 = 1.f - fx;                                  \
        float ycf0 = y0f, ycf1 = y0f + 1.f, xcf0 = x0f, xcf1 = x0f + 1.f;      \
        bool vy0 = (ycf0 >= 0.f) && (ycf0 <= 55.f);                            \
        bool vy1 = (ycf1 >= 0.f) && (ycf1 <= 55.f);                            \
        bool vx0 = (xcf0 >= 0.f) && (xcf0 <= 55.f);                            \
        bool vx1 = (xcf1 >= 0.f) && (xcf1 <= 55.f);                            \
        int yi0 = min(max((int)ycf0, 0), 55), yi1 = min(max((int)ycf1, 0), 55); \
        int xi0 = min(max((int)xcf0, 0), 55), xi1 = min(max((int)xcf1, 0), 55); \
        cidx0 = yi0 * 56 + xi0; cwgt0 = (vy0 && vx0) ? wy0 * wx0 : 0.f;        \
        cidx1 = yi0 * 56 + xi1; cwgt1 = (vy0 && vx1) ? wy0 * fx : 0.f;         \
        cidx2 = yi1 * 56 + xi0; cwgt2 = (vy1 && vx0) ? fy * wx0 : 0.f;         \
        cidx3 = yi1 * 56 + xi1; cwgt3 = (vy1 && vx1) ? fy * fx : 0.f;          \
    }

#define STAGE_A(S, BUF)                                                        \
    {                                                                          \
        _Pragma("unroll")                                                      \
        for (int i = 0; i < 4; i++) {                                          \
            int q = t + 512 * i;                                               \
            int row = q >> 3;                                                  \
            int part = (q & 7) ^ (row & 7);                                    \
            gload_lds16(W2 + (size_t)row * RDIM + (S) * 64 + part * 8,         \
                        &lA[BUF][(size_t)(wid * 64 + 512 * i) * 8]);           \
        }                                                                      \
    }

#define GATHERS(S)                                                             \
    {                                                                          \
        int c0g = ((S) & 3) * 64 + bcg * 8;                                    \
        nv0 = *(const u32x4*)(xb + (size_t)cidx0 * CH + c0g);                  \
        nv1 = *(const u32x4*)(xb + (size_t)cidx1 * CH + c0g);                  \
        nv2 = *(const u32x4*)(xb + (size_t)cidx2 * CH + c0g);                  \
        nv3 = *(const u32x4*)(xb + (size_t)cidx3 * CH + c0g);                  \
    }

#define BLEND_WRITE(BUF)                                                       \
    {                                                                          \
        float al[4] = {0.f, 0.f, 0.f, 0.f};                                    \
        float ah[4] = {0.f, 0.f, 0.f, 0.f};                                    \
        _Pragma("unroll")                                                      \
        for (int i = 0; i < 4; i++) {                                          \
            al[i] = fmaf(cwgt0, __uint_as_float(nv0[i] << 16),                 \
                    fmaf(cwgt1, __uint_as_float(nv1[i] << 16),                 \
                    fmaf(cwgt2, __uint_as_float(nv2[i] << 16),                 \
                         cwgt3 * __uint_as_float(nv3[i] << 16))));             \
            ah[i] = fmaf(cwgt0, __uint_as_float(nv0[i] & 0xffff0000u),         \
                    fmaf(cwgt1, __uint_as_float(nv1[i] & 0xffff0000u),         \
                    fmaf(cwgt2, __uint_as_float(nv2[i] & 0xffff0000u),         \
                         cwgt3 * __uint_as_float(nv3[i] & 0xffff0000u))));     \
        }                                                                      \
        u32x4 ov;                                                              \
        _Pragma("unroll")                                                      \
        for (int i = 0; i < 4; i++) ov[i] = cvtpk(al[i], ah[i]);               \
        *(u32x4*)(&lB[BUF][lboff]) = ov;                                       \
    }

    // ---- prologue: lB[0] = B(step0); nv = gathers(step1); lA = A(step0) ----
    {
        float oy = off[(size_t)(b * 18 + 0) * HW + hw];
        float ox = off[(size_t)(b * 18 + 1) * HW + hw];
        META_COMPUTE(0, oy, ox);
    }
    GATHERS(0);
    STAGE_A(0, 0);
    offYn = off[(size_t)(b * 18 + 2) * HW + hw];
    offXn = off[(size_t)(b * 18 + 3) * HW + hw];
    BLEND_WRITE(0);
    __syncthreads();

    // ---- main loop: one barrier per K-step ----
    for (int s = 0; s < 36; ++s) {
        int cur = s & 1;
        int nxt = cur ^ 1;
        if (s < 35) {
            int s1 = s + 1;
            if ((s1 & 3) == 0) {
                int tap1 = s1 >> 2;
                META_COMPUTE(tap1, offYn, offXn);
                if (tap1 < 8) {
                    offYn = off[(size_t)(b * 18 + 2 * tap1 + 2) * HW + hw];
                    offXn = off[(size_t)(b * 18 + 2 * tap1 + 3) * HW + hw];
                }
            }
            GATHERS(s1);
            STAGE_A(s1, nxt);
        }
        // MFMA cluster on buffers[cur] (prefetch latency hides under this)
        __builtin_amdgcn_s_setprio(1);
#pragma unroll
        for (int kk = 0; kk < 2; kk++) {
            bf16x8 afr[4], bfr[2];
#pragma unroll
            for (int m = 0; m < 4; m++) {
                int row = m_off + m * 16 + fr;
                int slot = (kk * 4 + fq) ^ (row & 7);
                afr[m] = *(const bf16x8*)&lA[cur][row * BK + slot * 8];
            }
#pragma unroll
            for (int n = 0; n < 2; n++) {
                int row = n_off + n * 16 + fr;
                int slot = (kk * 4 + fq) ^ (row & 7);
                bfr[n] = *(const bf16x8*)&lB[cur][row * BK + slot * 8];
            }
#pragma unroll
            for (int m = 0; m < 4; m++)
#pragma unroll
                for (int n = 0; n < 2; n++)
                    acc[m][n] = __builtin_amdgcn_mfma_f32_16x16x32_bf16(afr[m], bfr[n], acc[m][n], 0, 0, 0);
        }
        __builtin_amdgcn_s_setprio(0);
        if (s < 35) {
            BLEND_WRITE(nxt);   // compiler inserts vmcnt for nv* before use
        }
        __syncthreads();        // drains STAGE_A vmcnt + ds_write lgkm; one barrier/step
    }

    // --- y write (pre-BN conv output) ---
    float* yb = y + (size_t)b * CH * HW;
#pragma unroll
    for (int m = 0; m < 4; m++) {
        int o = m_off + m * 16 + fq * 4;
#pragma unroll
        for (int n = 0; n < 2; n++) {
            int p = n0 + n_off + n * 16 + fr;
#pragma unroll
            for (int jj = 0; jj < 4; jj++)
                yb[(size_t)(o + jj) * HW + p] = acc[m][n][jj];
        }
    }

    // --- BN partial sums: reduce over n and fr within each fq group ---
    int blk2 = (b * 49 + spat) * 2 + (wid & 1);
#pragma unroll
    for (int m = 0; m < 4; m++)
#pragma unroll
        for (int jj = 0; jj < 4; jj++) {
            float s = acc[m][0][jj] + acc[m][1][jj];
            float q = acc[m][0][jj] * acc[m][0][jj] + acc[m][1][jj] * acc[m][1][jj];
#pragma unroll
            for (int msk = 1; msk < 16; msk <<= 1) {
                s += __shfl_xor(s, msk);
                q += __shfl_xor(q, msk);
            }
            if (fr == 0) {
                int o = m_off + m * 16 + fq * 4 + jj;
                psum_s[(size_t)o * NCOL + blk2] = s;
                psum_q[(size_t)o * NCOL + blk2] = q;
            }
        }
}

// ---------------- 4. reduce partials -> scale/shift ----------------
__global__ __launch_bounds__(256) void k_stats2(const float* __restrict__ psum_s,
                                                const float* __restrict__ psum_q,
                                                const float* __restrict__ gamma,
                                                const float* __restrict__ beta,
                                                float* __restrict__ scaleArr,
                                                float* __restrict__ shiftArr) {
    int o = blockIdx.x;
    int t = threadIdx.x;
    float s = 0.f, q = 0.f;
    for (int i = t; i < NCOL; i += 256) {
        s += psum_s[(size_t)o * NCOL + i];
        q += psum_q[(size_t)o * NCOL + i];
    }
    __shared__ float r1[256], r2[256];
    r1[t] = s; r2[t] = q;
    __syncthreads();
    for (int st = 128; st > 0; st >>= 1) {
        if (t < st) { r1[t] += r1[t + st]; r2[t] += r2[t + st]; }
        __syncthreads();
    }
    if (t == 0) {
        float inv = 1.f / (float)NPOS;
        float mean = r1[0] * inv;
        float var  = r2[0] * inv - mean * mean;
        float sc = gamma[o] * rsqrtf(var + EPSV);
        scaleArr[o] = sc;
        shiftArr[o] = beta[o] - mean * sc;
    }
}

// ---------------- 5. normalize + ReLU (in place on d_out) ----------------
__global__ __launch_bounds__(256) void k_norm(float* __restrict__ y,
                                              const float* __restrict__ scaleArr,
                                              const float* __restrict__ shiftArr) {
    const int total4 = NBAT * CH * (HW / 4);
    for (int i = blockIdx.x * 256 + threadIdx.x; i < total4; i += gridDim.x * 256) {
        int o = (i / (HW / 4)) & 255;
        float sc = scaleArr[o], sh = shiftArr[o];
        float4 v = ((const float4*)y)[i];
        float4 r;
        r.x = fmaxf(v.x * sc + sh, 0.f);
        r.y = fmaxf(v.y * sc + sh, 0.f);
        r.z = fmaxf(v.z * sc + sh, 0.f);
        r.w = fmaxf(v.w * sc + sh, 0.f);
        ((float4*)y)[i] = r;
    }
}

extern "C" void kernel_launch(void* const* d_in, const int* in_sizes, int n_in,
                              void* d_out, int out_size, void* d_ws, size_t ws_size,
                              hipStream_t stream) {
    const float* x     = (const float*)d_in[0];
    const float* off   = (const float*)d_in[1];
    const float* wgt   = (const float*)d_in[2];
    const float* gamma = (const float*)d_in[3];
    const float* beta  = (const float*)d_in[4];
    float* out = (float*)d_out;     // pre-BN conv output, normalized in place
    char* ws = (char*)d_ws;

    // workspace layout (min ~30.1 MB)
    unsigned short* W2 = (unsigned short*)(ws + 0);          //  1,179,648 B
    unsigned short* xt = (unsigned short*)(ws + 1179648);    // 25,690,112 B
    float* psum_s      = (float*)(ws + 26869760);            //  1,605,632 B
    float* psum_q      = (float*)(ws + 28475392);            //  1,605,632 B
    float* scaleArr    = (float*)(ws + 30081024);            //      1,024 B
    float* shiftArr    = (float*)(ws + 30082048);            //      1,024 B

    k_transpose<<<dim3(49, 4, 16), 256, 0, stream>>>(x, xt);
    k_w2<<<2304, 256, 0, stream>>>(wgt, W2);
    k_fgemm<<<784, 512, 0, stream>>>(xt, off, W2, out, psum_s, psum_q);
    k_stats2<<<256, 256, 0, stream>>>(psum_s, psum_q, gamma, beta, scaleArr, shiftArr);
    k_norm<<<2048, 256, 0, stream>>>(out, scaleArr, shiftArr);
}

// Round 14
// 161.180 us; speedup vs baseline: 2.3918x; 1.0145x over previous
//
#include <hip/hip_runtime.h>
#include <stdint.h>

#define HW    3136
#define CH    256
#define NBAT  16
#define RDIM  2304          // CH * 9
#define NPOS  50176         // NBAT * HW
#define EPSV  1e-5f
#define NCOL  1568          // 784 blocks * 2 halves

typedef __bf16 bf16x8 __attribute__((ext_vector_type(8)));
typedef float  f32x4  __attribute__((ext_vector_type(4)));
typedef unsigned int u32x4 __attribute__((ext_vector_type(4)));

__device__ __forceinline__ unsigned short f2bf(float f) {
    union { float f; unsigned int u; } z; z.f = f;
    unsigned int u = z.u;
    u += 0x7FFFu + ((u >> 16) & 1u);     // round-to-nearest-even
    return (unsigned short)(u >> 16);
}

__device__ __forceinline__ unsigned int cvtpk(float lo, float hi) {
    unsigned int r;
    asm("v_cvt_pk_bf16_f32 %0, %1, %2" : "=v"(r) : "v"(lo), "v"(hi));
    return r;
}

__device__ __forceinline__ void gload_lds16(const void* g, void* l) {
    __builtin_amdgcn_global_load_lds(
        (const __attribute__((address_space(1))) unsigned int*)g,
        (__attribute__((address_space(3))) unsigned int*)l,
        16, 0, 0);
}

// ------- 1+2 merged. Blocks 0..3135: transpose x -> x_t bf16. Blocks 3136..5439: W2 reorder.
__global__ __launch_bounds__(256) void k_prep(const float* __restrict__ x,
                                              const float* __restrict__ wgt,
                                              unsigned short* __restrict__ xt,
                                              unsigned short* __restrict__ w2) {
    __shared__ float tile[64][65];
    int id = blockIdx.x;
    if (id < 3136) {
        int bx = id % 49;
        int by = (id / 49) & 3;
        int bz = id / 196;
        int hw0 = bx * 64;
        int c0  = by * 64;
        int b   = bz;
        int tx = threadIdx.x & 63;
        int ty = threadIdx.x >> 6;
        const float* xp = x + ((size_t)(b * CH + c0)) * HW + hw0;
#pragma unroll
        for (int i = 0; i < 16; i++) {
            int c_l = ty + i * 4;
            tile[c_l][tx] = xp[(size_t)c_l * HW + tx];
        }
        __syncthreads();
        unsigned short* op = xt + ((size_t)(b * HW + hw0)) * CH + c0;
#pragma unroll
        for (int i = 0; i < 16; i++) {
            int hw_l = ty + i * 4;
            op[(size_t)hw_l * CH + tx] = f2bf(tile[tx][hw_l]);
        }
    } else {
        int idx = (id - 3136) * 256 + threadIdx.x;   // exactly 589824 threads
        int c = idx & 255;
        int k = (idx >> 8) % 9;
        int o = idx / RDIM;
        w2[idx] = f2bf(wgt[o * RDIM + c * 9 + k]);
    }
}

// ---------------- 3. fused im2col-sample + GEMM + BN partial sums ----------------
// XCD-aware: bid%8 = XCD owns 2 batches (L2-resident x_t; round 7: FETCH 24MB).
// PROVEN (R9/R13): double-buffered lA/lB, ONE barrier per K-step; next step's
// gathers + A-stage issued BEFORE the MFMA cluster so L2 latency hides under MFMA.
// *** FROZEN: three semantically-equivalent rewrites (R10/R11/R12) all failed. ***
#define BK 64
__global__ __launch_bounds__(512, 4) void k_fgemm(const unsigned short* __restrict__ xt,
                                                  const float* __restrict__ off,
                                                  const unsigned short* __restrict__ W2,
                                                  float* __restrict__ y,
                                                  float* __restrict__ psum_s,
                                                  float* __restrict__ psum_q) {
    __shared__ __align__(16) unsigned short lA[2][256 * BK];  // 64 KB
    __shared__ __align__(16) unsigned short lB[2][64 * BK];   // 16 KB
    int t    = threadIdx.x;
    int wid  = t >> 6;
    int lane = t & 63;

    int bid  = blockIdx.x;
    int xcd  = bid & 7;
    int j    = bid >> 3;                 // 0..97
    int b    = 2 * xcd + (j >= 49 ? 1 : 0);
    int spat = (j >= 49) ? j - 49 : j;
    int n0   = spat * 64;
    const unsigned short* xb = xt + (size_t)b * HW * CH;

    int m_off = (wid >> 1) * 64;
    int n_off = (wid & 1) * 32;
    int fr = lane & 15;
    int fq = lane >> 4;

    // B-fill role: position bp (0..63), channel-group bcg (8 ch)
    int bp  = t >> 3;
    int bcg = t & 7;
    int hw = n0 + bp;
    int h = hw / 56, w = hw - h * 56;
    int lboff = bp * BK + ((bcg ^ (bp & 7)) * 8);   // swizzled LDS slot

    f32x4 acc[4][2];
#pragma unroll
    for (int m = 0; m < 4; m++)
#pragma unroll
        for (int n = 0; n < 2; n++)
            acc[m][n] = (f32x4){0.f, 0.f, 0.f, 0.f};

    int   cidx0, cidx1, cidx2, cidx3;
    float cwgt0, cwgt1, cwgt2, cwgt3;
    u32x4 nv0, nv1, nv2, nv3;
    float offYn, offXn;

    // meta from (oy,ox) for tap -> corner idx/wgt
#define META_COMPUTE(TAP, OY, OX)                                              \
    {                                                                          \
        float py = (float)(h + (TAP) / 3 - 1) + (OY);                          \
        float px = (float)(w + (TAP) % 3 - 1) + (OX);                          \
        float y0f = floorf(py), x0f = floorf(px);                              \
        float fy = py - y0f, fx = px - x0f;                                    \
        float wy0 = 1.f - fy, wx0 = 1.f - fx;                                  \
        float ycf0 = y0f, ycf1 = y0f + 1.f, xcf0 = x0f, xcf1 = x0f + 1.f;      \
        bool vy0 = (ycf0 >= 0.f) && (ycf0 <= 55.f);                            \
        bool vy1 = (ycf1 >= 0.f) && (ycf1 <= 55.f);                            \
        bool vx0 = (xcf0 >= 0.f) && (xcf0 <= 55.f);                            \
        bool vx1 = (xcf1 >= 0.f) && (xcf1 <= 55.f);                            \
        int yi0 = min(max((int)ycf0, 0), 55), yi1 = min(max((int)ycf1, 0), 55); \
        int xi0 = min(max((int)xcf0, 0), 55), xi1 = min(max((int)xcf1, 0), 55); \
        cidx0 = yi0 * 56 + xi0; cwgt0 = (vy0 && vx0) ? wy0 * wx0 : 0.f;        \
        cidx1 = yi0 * 56 + xi1; cwgt1 = (vy0 && vx1) ? wy0 * fx : 0.f;         \
        cidx2 = yi1 * 56 + xi0; cwgt2 = (vy1 && vx0) ? fy * wx0 : 0.f;         \
        cidx3 = yi1 * 56 + xi1; cwgt3 = (vy1 && vx1) ? fy * fx : 0.f;          \
    }

#define STAGE_A(S, BUF)                                                        \
    {                                                                          \
        _Pragma("unroll")                                                      \
        for (int i = 0; i < 4; i++) {                                          \
            int q = t + 512 * i;                                               \
            int row = q >> 3;                                                  \
            int part = (q & 7) ^ (row & 7);                                    \
            gload_lds16(W2 + (size_t)row * RDIM + (S) * 64 + part * 8,         \
                        &lA[BUF][(size_t)(wid * 64 + 512 * i) * 8]);           \
        }                                                                      \
    }

#define GATHERS(S)                                                             \
    {                                                                          \
        int c0g = ((S) & 3) * 64 + bcg * 8;                                    \
        nv0 = *(const u32x4*)(xb + (size_t)cidx0 * CH + c0g);                  \
        nv1 = *(const u32x4*)(xb + (size_t)cidx1 * CH + c0g);                  \
        nv2 = *(const u32x4*)(xb + (size_t)cidx2 * CH + c0g);                  \
        nv3 = *(const u32x4*)(xb + (size_t)cidx3 * CH + c0g);                  \
    }

#define BLEND_WRITE(BUF)                                                       \
    {                                                                          \
        float al[4] = {0.f, 0.f, 0.f, 0.f};                                    \
        float ah[4] = {0.f, 0.f, 0.f, 0.f};                                    \
        _Pragma("unroll")                                                      \
        for (int i = 0; i < 4; i++) {                                          \
            al[i] = fmaf(cwgt0, __uint_as_float(nv0[i] << 16),                 \
                    fmaf(cwgt1, __uint_as_float(nv1[i] << 16),                 \
                    fmaf(cwgt2, __uint_as_float(nv2[i] << 16),                 \
                         cwgt3 * __uint_as_float(nv3[i] << 16))));             \
            ah[i] = fmaf(cwgt0, __uint_as_float(nv0[i] & 0xffff0000u),         \
                    fmaf(cwgt1, __uint_as_float(nv1[i] & 0xffff0000u),         \
                    fmaf(cwgt2, __uint_as_float(nv2[i] & 0xffff0000u),         \
                         cwgt3 * __uint_as_float(nv3[i] & 0xffff0000u))));     \
        }                                                                      \
        u32x4 ov;                                                              \
        _Pragma("unroll")                                                      \
        for (int i = 0; i < 4; i++) ov[i] = cvtpk(al[i], ah[i]);               \
        *(u32x4*)(&lB[BUF][lboff]) = ov;                                       \
    }

    // ---- prologue: lB[0] = B(step0); nv = gathers(step1); lA = A(step0) ----
    {
        float oy = off[(size_t)(b * 18 + 0) * HW + hw];
        float ox = off[(size_t)(b * 18 + 1) * HW + hw];
        META_COMPUTE(0, oy, ox);
    }
    GATHERS(0);
    STAGE_A(0, 0);
    offYn = off[(size_t)(b * 18 + 2) * HW + hw];
    offXn = off[(size_t)(b * 18 + 3) * HW + hw];
    BLEND_WRITE(0);
    __syncthreads();

    // ---- main loop: one barrier per K-step ----
    for (int s = 0; s < 36; ++s) {
        int cur = s & 1;
        int nxt = cur ^ 1;
        if (s < 35) {
            int s1 = s + 1;
            if ((s1 & 3) == 0) {
                int tap1 = s1 >> 2;
                META_COMPUTE(tap1, offYn, offXn);
                if (tap1 < 8) {
                    offYn = off[(size_t)(b * 18 + 2 * tap1 + 2) * HW + hw];
                    offXn = off[(size_t)(b * 18 + 2 * tap1 + 3) * HW + hw];
                }
            }
            GATHERS(s1);
            STAGE_A(s1, nxt);
        }
        // MFMA cluster on buffers[cur] (prefetch latency hides under this)
        __builtin_amdgcn_s_setprio(1);
#pragma unroll
        for (int kk = 0; kk < 2; kk++) {
            bf16x8 afr[4], bfr[2];
#pragma unroll
            for (int m = 0; m < 4; m++) {
                int row = m_off + m * 16 + fr;
                int slot = (kk * 4 + fq) ^ (row & 7);
                afr[m] = *(const bf16x8*)&lA[cur][row * BK + slot * 8];
            }
#pragma unroll
            for (int n = 0; n < 2; n++) {
                int row = n_off + n * 16 + fr;
                int slot = (kk * 4 + fq) ^ (row & 7);
                bfr[n] = *(const bf16x8*)&lB[cur][row * BK + slot * 8];
            }
#pragma unroll
            for (int m = 0; m < 4; m++)
#pragma unroll
                for (int n = 0; n < 2; n++)
                    acc[m][n] = __builtin_amdgcn_mfma_f32_16x16x32_bf16(afr[m], bfr[n], acc[m][n], 0, 0, 0);
        }
        __builtin_amdgcn_s_setprio(0);
        if (s < 35) {
            BLEND_WRITE(nxt);   // compiler inserts vmcnt for nv* before use
        }
        __syncthreads();        // drains STAGE_A vmcnt + ds_write lgkm; one barrier/step
    }

    // --- y write (pre-BN conv output) ---
    float* yb = y + (size_t)b * CH * HW;
#pragma unroll
    for (int m = 0; m < 4; m++) {
        int o = m_off + m * 16 + fq * 4;
#pragma unroll
        for (int n = 0; n < 2; n++) {
            int p = n0 + n_off + n * 16 + fr;
#pragma unroll
            for (int jj = 0; jj < 4; jj++)
                yb[(size_t)(o + jj) * HW + p] = acc[m][n][jj];
        }
    }

    // --- BN partial sums: reduce over n and fr within each fq group ---
    int blk2 = (b * 49 + spat) * 2 + (wid & 1);
#pragma unroll
    for (int m = 0; m < 4; m++)
#pragma unroll
        for (int jj = 0; jj < 4; jj++) {
            float s = acc[m][0][jj] + acc[m][1][jj];
            float q = acc[m][0][jj] * acc[m][0][jj] + acc[m][1][jj] * acc[m][1][jj];
#pragma unroll
            for (int msk = 1; msk < 16; msk <<= 1) {
                s += __shfl_xor(s, msk);
                q += __shfl_xor(q, msk);
            }
            if (fr == 0) {
                int o = m_off + m * 16 + fq * 4 + jj;
                psum_s[(size_t)o * NCOL + blk2] = s;
                psum_q[(size_t)o * NCOL + blk2] = q;
            }
        }
}

// ---------------- 4. reduce partials -> scale/shift ----------------
__global__ __launch_bounds__(256) void k_stats2(const float* __restrict__ psum_s,
                                                const float* __restrict__ psum_q,
                                                const float* __restrict__ gamma,
                                                const float* __restrict__ beta,
                                                float* __restrict__ scaleArr,
                                                float* __restrict__ shiftArr) {
    int o = blockIdx.x;
    int t = threadIdx.x;
    float s = 0.f, q = 0.f;
    for (int i = t; i < NCOL; i += 256) {
        s += psum_s[(size_t)o * NCOL + i];
        q += psum_q[(size_t)o * NCOL + i];
    }
    __shared__ float r1[256], r2[256];
    r1[t] = s; r2[t] = q;
    __syncthreads();
    for (int st = 128; st > 0; st >>= 1) {
        if (t < st) { r1[t] += r1[t + st]; r2[t] += r2[t + st]; }
        __syncthreads();
    }
    if (t == 0) {
        float inv = 1.f / (float)NPOS;
        float mean = r1[0] * inv;
        float var  = r2[0] * inv - mean * mean;
        float sc = gamma[o] * rsqrtf(var + EPSV);
        scaleArr[o] = sc;
        shiftArr[o] = beta[o] - mean * sc;
    }
}

// ---------------- 5. normalize + ReLU (in place on d_out) ----------------
__global__ __launch_bounds__(256) void k_norm(float* __restrict__ y,
                                              const float* __restrict__ scaleArr,
                                              const float* __restrict__ shiftArr) {
    const int total4 = NBAT * CH * (HW / 4);
    for (int i = blockIdx.x * 256 + threadIdx.x; i < total4; i += gridDim.x * 256) {
        int o = (i / (HW / 4)) & 255;
        float sc = scaleArr[o], sh = shiftArr[o];
        float4 v = ((const float4*)y)[i];
        float4 r;
        r.x = fmaxf(v.x * sc + sh, 0.f);
        r.y = fmaxf(v.y * sc + sh, 0.f);
        r.z = fmaxf(v.z * sc + sh, 0.f);
        r.w = fmaxf(v.w * sc + sh, 0.f);
        ((float4*)y)[i] = r;
    }
}

extern "C" void kernel_launch(void* const* d_in, const int* in_sizes, int n_in,
                              void* d_out, int out_size, void* d_ws, size_t ws_size,
                              hipStream_t stream) {
    const float* x     = (const float*)d_in[0];
    const float* off   = (const float*)d_in[1];
    const float* wgt   = (const float*)d_in[2];
    const float* gamma = (const float*)d_in[3];
    const float* beta  = (const float*)d_in[4];
    float* out = (float*)d_out;     // pre-BN conv output, normalized in place
    char* ws = (char*)d_ws;

    // workspace layout (min ~30.1 MB)
    unsigned short* W2 = (unsigned short*)(ws + 0);          //  1,179,648 B
    unsigned short* xt = (unsigned short*)(ws + 1179648);    // 25,690,112 B
    float* psum_s      = (float*)(ws + 26869760);            //  1,605,632 B
    float* psum_q      = (float*)(ws + 28475392);            //  1,605,632 B
    float* scaleArr    = (float*)(ws + 30081024);            //      1,024 B
    float* shiftArr    = (float*)(ws + 30082048);            //      1,024 B

    k_prep<<<5440, 256, 0, stream>>>(x, wgt, xt, W2);
    k_fgemm<<<784, 512, 0, stream>>>(xt, off, W2, out, psum_s, psum_q);
    k_stats2<<<256, 256, 0, stream>>>(psum_s, psum_q, gamma, beta, scaleArr, shiftArr);
    k_norm<<<2048, 256, 0, stream>>>(out, scaleArr, shiftArr);
}

// Round 15
// 160.485 us; speedup vs baseline: 2.4022x; 1.0043x over previous
//
#include <hip/hip_runtime.h>
#include <stdint.h>

#define HW    3136
#define CH    256
#define NBAT  16
#define RDIM  2304          // CH * 9
#define NPOS  50176         // NBAT * HW
#define EPSV  1e-5f
#define NCOL  1568          // 784 blocks * 2 halves

typedef __bf16 bf16x8 __attribute__((ext_vector_type(8)));
typedef float  f32x4  __attribute__((ext_vector_type(4)));
typedef float  f32x2  __attribute__((ext_vector_type(2)));
typedef unsigned int u32x4 __attribute__((ext_vector_type(4)));

__device__ __forceinline__ unsigned short f2bf(float f) {
    union { float f; unsigned int u; } z; z.f = f;
    unsigned int u = z.u;
    u += 0x7FFFu + ((u >> 16) & 1u);     // round-to-nearest-even
    return (unsigned short)(u >> 16);
}

__device__ __forceinline__ unsigned int cvtpk(float lo, float hi) {
    unsigned int r;
    asm("v_cvt_pk_bf16_f32 %0, %1, %2" : "=v"(r) : "v"(lo), "v"(hi));
    return r;
}

__device__ __forceinline__ f32x2 pkmul(f32x2 a, f32x2 b) {
    f32x2 d;
    asm("v_pk_mul_f32 %0, %1, %2" : "=v"(d) : "v"(a), "v"(b));
    return d;
}

__device__ __forceinline__ f32x2 pkfma(f32x2 a, f32x2 b, f32x2 c) {
    f32x2 d;
    asm("v_pk_fma_f32 %0, %1, %2, %3" : "=v"(d) : "v"(a), "v"(b), "v"(c));
    return d;
}

__device__ __forceinline__ void gload_lds16(const void* g, void* l) {
    __builtin_amdgcn_global_load_lds(
        (const __attribute__((address_space(1))) unsigned int*)g,
        (__attribute__((address_space(3))) unsigned int*)l,
        16, 0, 0);
}

// ------- 1+2 merged. Blocks 0..3135: transpose x -> x_t bf16. Blocks 3136..5439: W2 reorder.
__global__ __launch_bounds__(256) void k_prep(const float* __restrict__ x,
                                              const float* __restrict__ wgt,
                                              unsigned short* __restrict__ xt,
                                              unsigned short* __restrict__ w2) {
    __shared__ float tile[64][65];
    int id = blockIdx.x;
    if (id < 3136) {
        int bx = id % 49;
        int by = (id / 49) & 3;
        int bz = id / 196;
        int hw0 = bx * 64;
        int c0  = by * 64;
        int b   = bz;
        int tx = threadIdx.x & 63;
        int ty = threadIdx.x >> 6;
        const float* xp = x + ((size_t)(b * CH + c0)) * HW + hw0;
#pragma unroll
        for (int i = 0; i < 16; i++) {
            int c_l = ty + i * 4;
            tile[c_l][tx] = xp[(size_t)c_l * HW + tx];
        }
        __syncthreads();
        unsigned short* op = xt + ((size_t)(b * HW + hw0)) * CH + c0;
#pragma unroll
        for (int i = 0; i < 16; i++) {
            int hw_l = ty + i * 4;
            op[(size_t)hw_l * CH + tx] = f2bf(tile[tx][hw_l]);
        }
    } else {
        int idx = (id - 3136) * 256 + threadIdx.x;   // exactly 589824 threads
        int c = idx & 255;
        int k = (idx >> 8) % 9;
        int o = idx / RDIM;
        w2[idx] = f2bf(wgt[o * RDIM + c * 9 + k]);
    }
}

// ---------------- 3. fused im2col-sample + GEMM + BN partial sums ----------------
// XCD-aware: bid%8 = XCD owns 2 batches (L2-resident x_t; round 7: FETCH 24MB).
// PROVEN (R9/R13/R14): double-buffered lA/lB, ONE barrier per K-step; next step's
// gathers + A-stage issued BEFORE the MFMA cluster so L2 latency hides under MFMA.
// *** Sync structure FROZEN: three equivalent-looking rewrites (R10/R11/R12) failed.
// *** R15 change is arithmetic-only inside BLEND_WRITE (v_pk_fma_f32, bit-identical).
#define BK 64
__global__ __launch_bounds__(512, 4) void k_fgemm(const unsigned short* __restrict__ xt,
                                                  const float* __restrict__ off,
                                                  const unsigned short* __restrict__ W2,
                                                  float* __restrict__ y,
                                                  float* __restrict__ psum_s,
                                                  float* __restrict__ psum_q) {
    __shared__ __align__(16) unsigned short lA[2][256 * BK];  // 64 KB
    __shared__ __align__(16) unsigned short lB[2][64 * BK];   // 16 KB
    int t    = threadIdx.x;
    int wid  = t >> 6;
    int lane = t & 63;

    int bid  = blockIdx.x;
    int xcd  = bid & 7;
    int j    = bid >> 3;                 // 0..97
    int b    = 2 * xcd + (j >= 49 ? 1 : 0);
    int spat = (j >= 49) ? j - 49 : j;
    int n0   = spat * 64;
    const unsigned short* xb = xt + (size_t)b * HW * CH;

    int m_off = (wid >> 1) * 64;
    int n_off = (wid & 1) * 32;
    int fr = lane & 15;
    int fq = lane >> 4;

    // B-fill role: position bp (0..63), channel-group bcg (8 ch)
    int bp  = t >> 3;
    int bcg = t & 7;
    int hw = n0 + bp;
    int h = hw / 56, w = hw - h * 56;
    int lboff = bp * BK + ((bcg ^ (bp & 7)) * 8);   // swizzled LDS slot

    f32x4 acc[4][2];
#pragma unroll
    for (int m = 0; m < 4; m++)
#pragma unroll
        for (int n = 0; n < 2; n++)
            acc[m][n] = (f32x4){0.f, 0.f, 0.f, 0.f};

    int   cidx0, cidx1, cidx2, cidx3;
    float cwgt0, cwgt1, cwgt2, cwgt3;
    f32x2 wp0, wp1, wp2, wp3;
    u32x4 nv0, nv1, nv2, nv3;
    float offYn, offXn;

    // meta from (oy,ox) for tap -> corner idx/wgt (+ packed weight pairs)
#define META_COMPUTE(TAP, OY, OX)                                              \
    {                                                                          \
        float py = (float)(h + (TAP) / 3 - 1) + (OY);                          \
        float px = (float)(w + (TAP) % 3 - 1) + (OX);                          \
        float y0f = floorf(py), x0f = floorf(px);                              \
        float fy = py - y0f, fx = px - x0f;                                    \
        float wy0 = 1.f - fy, wx0 = 1.f - fx;                                  \
        float ycf0 = y0f, ycf1 = y0f + 1.f, xcf0 = x0f, xcf1 = x0f + 1.f;      \
        bool vy0 = (ycf0 >= 0.f) && (ycf0 <= 55.f);                            \
        bool vy1 = (ycf1 >= 0.f) && (ycf1 <= 55.f);                            \
        bool vx0 = (xcf0 >= 0.f) && (xcf0 <= 55.f);                            \
        bool vx1 = (xcf1 >= 0.f) && (xcf1 <= 55.f);                            \
        int yi0 = min(max((int)ycf0, 0), 55), yi1 = min(max((int)ycf1, 0), 55); \
        int xi0 = min(max((int)xcf0, 0), 55), xi1 = min(max((int)xcf1, 0), 55); \
        cidx0 = yi0 * 56 + xi0; cwgt0 = (vy0 && vx0) ? wy0 * wx0 : 0.f;        \
        cidx1 = yi0 * 56 + xi1; cwgt1 = (vy0 && vx1) ? wy0 * fx : 0.f;         \
        cidx2 = yi1 * 56 + xi0; cwgt2 = (vy1 && vx0) ? fy * wx0 : 0.f;         \
        cidx3 = yi1 * 56 + xi1; cwgt3 = (vy1 && vx1) ? fy * fx : 0.f;          \
        wp0[0] = cwgt0; wp0[1] = cwgt0;                                        \
        wp1[0] = cwgt1; wp1[1] = cwgt1;                                        \
        wp2[0] = cwgt2; wp2[1] = cwgt2;                                        \
        wp3[0] = cwgt3; wp3[1] = cwgt3;                                        \
    }

#define STAGE_A(S, BUF)                                                        \
    {                                                                          \
        _Pragma("unroll")                                                      \
        for (int i = 0; i < 4; i++) {                                          \
            int q = t + 512 * i;                                               \
            int row = q >> 3;                                                  \
            int part = (q & 7) ^ (row & 7);                                    \
            gload_lds16(W2 + (size_t)row * RDIM + (S) * 64 + part * 8,         \
                        &lA[BUF][(size_t)(wid * 64 + 512 * i) * 8]);           \
        }                                                                      \
    }

#define GATHERS(S)                                                             \
    {                                                                          \
        int c0g = ((S) & 3) * 64 + bcg * 8;                                    \
        nv0 = *(const u32x4*)(xb + (size_t)cidx0 * CH + c0g);                  \
        nv1 = *(const u32x4*)(xb + (size_t)cidx1 * CH + c0g);                  \
        nv2 = *(const u32x4*)(xb + (size_t)cidx2 * CH + c0g);                  \
        nv3 = *(const u32x4*)(xb + (size_t)cidx3 * CH + c0g);                  \
    }

// packed blend: per word i, {al,ah} pair accumulates via v_pk_mul/v_pk_fma.
// association mirrors the proven scalar chain exactly:
//   al = fma(w0,lo0, fma(w1,lo1, fma(w2,lo2, mul(w3,lo3))))   (both halves)
#define BLEND_WRITE(BUF)                                                       \
    {                                                                          \
        u32x4 ov;                                                              \
        _Pragma("unroll")                                                      \
        for (int i = 0; i < 4; i++) {                                          \
            f32x2 v0, v1, v2, v3, ac;                                          \
            v0[0] = __uint_as_float(nv0[i] << 16);                             \
            v0[1] = __uint_as_float(nv0[i] & 0xffff0000u);                     \
            v1[0] = __uint_as_float(nv1[i] << 16);                             \
            v1[1] = __uint_as_float(nv1[i] & 0xffff0000u);                     \
            v2[0] = __uint_as_float(nv2[i] << 16);                             \
            v2[1] = __uint_as_float(nv2[i] & 0xffff0000u);                     \
            v3[0] = __uint_as_float(nv3[i] << 16);                             \
            v3[1] = __uint_as_float(nv3[i] & 0xffff0000u);                     \
            ac = pkmul(wp3, v3);                                               \
            ac = pkfma(wp2, v2, ac);                                           \
            ac = pkfma(wp1, v1, ac);                                           \
            ac = pkfma(wp0, v0, ac);                                           \
            ov[i] = cvtpk(ac[0], ac[1]);                                       \
        }                                                                      \
        *(u32x4*)(&lB[BUF][lboff]) = ov;                                       \
    }

    // ---- prologue: lB[0] = B(step0); nv = gathers(step1); lA = A(step0) ----
    {
        float oy = off[(size_t)(b * 18 + 0) * HW + hw];
        float ox = off[(size_t)(b * 18 + 1) * HW + hw];
        META_COMPUTE(0, oy, ox);
    }
    GATHERS(0);
    STAGE_A(0, 0);
    offYn = off[(size_t)(b * 18 + 2) * HW + hw];
    offXn = off[(size_t)(b * 18 + 3) * HW + hw];
    BLEND_WRITE(0);
    __syncthreads();

    // ---- main loop: one barrier per K-step ----
    for (int s = 0; s < 36; ++s) {
        int cur = s & 1;
        int nxt = cur ^ 1;
        if (s < 35) {
            int s1 = s + 1;
            if ((s1 & 3) == 0) {
                int tap1 = s1 >> 2;
                META_COMPUTE(tap1, offYn, offXn);
                if (tap1 < 8) {
                    offYn = off[(size_t)(b * 18 + 2 * tap1 + 2) * HW + hw];
                    offXn = off[(size_t)(b * 18 + 2 * tap1 + 3) * HW + hw];
                }
            }
            GATHERS(s1);
            STAGE_A(s1, nxt);
        }
        // MFMA cluster on buffers[cur] (prefetch latency hides under this)
        __builtin_amdgcn_s_setprio(1);
#pragma unroll
        for (int kk = 0; kk < 2; kk++) {
            bf16x8 afr[4], bfr[2];
#pragma unroll
            for (int m = 0; m < 4; m++) {
                int row = m_off + m * 16 + fr;
                int slot = (kk * 4 + fq) ^ (row & 7);
                afr[m] = *(const bf16x8*)&lA[cur][row * BK + slot * 8];
            }
#pragma unroll
            for (int n = 0; n < 2; n++) {
                int row = n_off + n * 16 + fr;
                int slot = (kk * 4 + fq) ^ (row & 7);
                bfr[n] = *(const bf16x8*)&lB[cur][row * BK + slot * 8];
            }
#pragma unroll
            for (int m = 0; m < 4; m++)
#pragma unroll
                for (int n = 0; n < 2; n++)
                    acc[m][n] = __builtin_amdgcn_mfma_f32_16x16x32_bf16(afr[m], bfr[n], acc[m][n], 0, 0, 0);
        }
        __builtin_amdgcn_s_setprio(0);
        if (s < 35) {
            BLEND_WRITE(nxt);   // compiler inserts vmcnt for nv* before use
        }
        __syncthreads();        // drains STAGE_A vmcnt + ds_write lgkm; one barrier/step
    }

    // --- y write (pre-BN conv output) ---
    float* yb = y + (size_t)b * CH * HW;
#pragma unroll
    for (int m = 0; m < 4; m++) {
        int o = m_off + m * 16 + fq * 4;
#pragma unroll
        for (int n = 0; n < 2; n++) {
            int p = n0 + n_off + n * 16 + fr;
#pragma unroll
            for (int jj = 0; jj < 4; jj++)
                yb[(size_t)(o + jj) * HW + p] = acc[m][n][jj];
        }
    }

    // --- BN partial sums: reduce over n and fr within each fq group ---
    int blk2 = (b * 49 + spat) * 2 + (wid & 1);
#pragma unroll
    for (int m = 0; m < 4; m++)
#pragma unroll
        for (int jj = 0; jj < 4; jj++) {
            float s = acc[m][0][jj] + acc[m][1][jj];
            float q = acc[m][0][jj] * acc[m][0][jj] + acc[m][1][jj] * acc[m][1][jj];
#pragma unroll
            for (int msk = 1; msk < 16; msk <<= 1) {
                s += __shfl_xor(s, msk);
                q += __shfl_xor(q, msk);
            }
            if (fr == 0) {
                int o = m_off + m * 16 + fq * 4 + jj;
                psum_s[(size_t)o * NCOL + blk2] = s;
                psum_q[(size_t)o * NCOL + blk2] = q;
            }
        }
}

// ---------------- 4. reduce partials -> scale/shift ----------------
__global__ __launch_bounds__(256) void k_stats2(const float* __restrict__ psum_s,
                                                const float* __restrict__ psum_q,
                                                const float* __restrict__ gamma,
                                                const float* __restrict__ beta,
                                                float* __restrict__ scaleArr,
                                                float* __restrict__ shiftArr) {
    int o = blockIdx.x;
    int t = threadIdx.x;
    float s = 0.f, q = 0.f;
    for (int i = t; i < NCOL; i += 256) {
        s += psum_s[(size_t)o * NCOL + i];
        q += psum_q[(size_t)o * NCOL + i];
    }
    __shared__ float r1[256], r2[256];
    r1[t] = s; r2[t] = q;
    __syncthreads();
    for (int st = 128; st > 0; st >>= 1) {
        if (t < st) { r1[t] += r1[t + st]; r2[t] += r2[t + st]; }
        __syncthreads();
    }
    if (t == 0) {
        float inv = 1.f / (float)NPOS;
        float mean = r1[0] * inv;
        float var  = r2[0] * inv - mean * mean;
        float sc = gamma[o] * rsqrtf(var + EPSV);
        scaleArr[o] = sc;
        shiftArr[o] = beta[o] - mean * sc;
    }
}

// ---------------- 5. normalize + ReLU (in place on d_out) ----------------
__global__ __launch_bounds__(256) void k_norm(float* __restrict__ y,
                                              const float* __restrict__ scaleArr,
                                              const float* __restrict__ shiftArr) {
    const int total4 = NBAT * CH * (HW / 4);
    for (int i = blockIdx.x * 256 + threadIdx.x; i < total4; i += gridDim.x * 256) {
        int o = (i / (HW / 4)) & 255;
        float sc = scaleArr[o], sh = shiftArr[o];
        float4 v = ((const float4*)y)[i];
        float4 r;
        r.x = fmaxf(v.x * sc + sh, 0.f);
        r.y = fmaxf(v.y * sc + sh, 0.f);
        r.z = fmaxf(v.z * sc + sh, 0.f);
        r.w = fmaxf(v.w * sc + sh, 0.f);
        ((float4*)y)[i] = r;
    }
}

extern "C" void kernel_launch(void* const* d_in, const int* in_sizes, int n_in,
                              void* d_out, int out_size, void* d_ws, size_t ws_size,
                              hipStream_t stream) {
    const float* x     = (const float*)d_in[0];
    const float* off   = (const float*)d_in[1];
    const float* wgt   = (const float*)d_in[2];
    const float* gamma = (const float*)d_in[3];
    const float* beta  = (const float*)d_in[4];
    float* out = (float*)d_out;     // pre-BN conv output, normalized in place
    char* ws = (char*)d_ws;

    // workspace layout (min ~30.1 MB)
    unsigned short* W2 = (unsigned short*)(ws + 0);          //  1,179,648 B
    unsigned short* xt = (unsigned short*)(ws + 1179648);    // 25,690,112 B
    float* psum_s      = (float*)(ws + 26869760);            //  1,605,632 B
    float* psum_q      = (float*)(ws + 28475392);            //  1,605,632 B
    float* scaleArr    = (float*)(ws + 30081024);            //      1,024 B
    float* shiftArr    = (float*)(ws + 30082048);            //      1,024 B

    k_prep<<<5440, 256, 0, stream>>>(x, wgt, xt, W2);
    k_fgemm<<<784, 512, 0, stream>>>(xt, off, W2, out, psum_s, psum_q);
    k_stats2<<<256, 256, 0, stream>>>(psum_s, psum_q, gamma, beta, scaleArr, shiftArr);
    k_norm<<<2048, 256, 0, stream>>>(out, scaleArr, shiftArr);
}

// Round 18
// 160.073 us; speedup vs baseline: 2.4083x; 1.0026x over previous
//
#include <hip/hip_runtime.h>
#include <stdint.h>

#define HW    3136
#define CH    256
#define NBAT  16
#define RDIM  2304          // CH * 9
#define NPOS  50176         // NBAT * HW
#define EPSV  1e-5f
#define NCOL  1568          // 784 blocks * 2 halves

typedef __bf16 bf16x8 __attribute__((ext_vector_type(8)));
typedef float  f32x4  __attribute__((ext_vector_type(4)));
typedef float  f32x2  __attribute__((ext_vector_type(2)));
typedef unsigned int u32x4 __attribute__((ext_vector_type(4)));

__device__ __forceinline__ unsigned short f2bf(float f) {
    union { float f; unsigned int u; } z; z.f = f;
    unsigned int u = z.u;
    u += 0x7FFFu + ((u >> 16) & 1u);     // round-to-nearest-even
    return (unsigned short)(u >> 16);
}

__device__ __forceinline__ unsigned int cvtpk(float lo, float hi) {
    unsigned int r;
    asm("v_cvt_pk_bf16_f32 %0, %1, %2" : "=v"(r) : "v"(lo), "v"(hi));
    return r;
}

__device__ __forceinline__ f32x2 pkmul(f32x2 a, f32x2 b) {
    f32x2 d;
    asm("v_pk_mul_f32 %0, %1, %2" : "=v"(d) : "v"(a), "v"(b));
    return d;
}

__device__ __forceinline__ f32x2 pkfma(f32x2 a, f32x2 b, f32x2 c) {
    f32x2 d;
    asm("v_pk_fma_f32 %0, %1, %2, %3" : "=v"(d) : "v"(a), "v"(b), "v"(c));
    return d;
}

__device__ __forceinline__ void gload_lds16(const void* g, void* l) {
    __builtin_amdgcn_global_load_lds(
        (const __attribute__((address_space(1))) unsigned int*)g,
        (__attribute__((address_space(3))) unsigned int*)l,
        16, 0, 0);
}

// ------- 1+2 merged. Blocks 0..3135: transpose x -> x_t bf16. Blocks 3136..5439: W2 reorder.
__global__ __launch_bounds__(256) void k_prep(const float* __restrict__ x,
                                              const float* __restrict__ wgt,
                                              unsigned short* __restrict__ xt,
                                              unsigned short* __restrict__ w2) {
    __shared__ float tile[64][65];
    int id = blockIdx.x;
    if (id < 3136) {
        int bx = id % 49;
        int by = (id / 49) & 3;
        int bz = id / 196;
        int hw0 = bx * 64;
        int c0  = by * 64;
        int b   = bz;
        int tx = threadIdx.x & 63;
        int ty = threadIdx.x >> 6;
        const float* xp = x + ((size_t)(b * CH + c0)) * HW + hw0;
#pragma unroll
        for (int i = 0; i < 16; i++) {
            int c_l = ty + i * 4;
            tile[c_l][tx] = xp[(size_t)c_l * HW + tx];
        }
        __syncthreads();
        unsigned short* op = xt + ((size_t)(b * HW + hw0)) * CH + c0;
#pragma unroll
        for (int i = 0; i < 16; i++) {
            int hw_l = ty + i * 4;
            op[(size_t)hw_l * CH + tx] = f2bf(tile[tx][hw_l]);
        }
    } else {
        int idx = (id - 3136) * 256 + threadIdx.x;   // exactly 589824 threads
        int c = idx & 255;
        int k = (idx >> 8) % 9;
        int o = idx / RDIM;
        w2[idx] = f2bf(wgt[o * RDIM + c * 9 + k]);
    }
}

// ---------------- 3. fused im2col-sample + GEMM + BN partial sums ----------------
// XCD-aware: bid%8 = XCD owns 2 batches (L2-resident x_t; FETCH 24MB).
// PROVEN (R9/R13/R14/R15): double-buffered lA/lB, ONE barrier per K-step; next
// step's gathers + A-stage issued BEFORE the MFMA cluster (latency under MFMA).
// *** Sync structure FROZEN: three equivalent-looking rewrites (R10/R11/R12)
// *** failed (races / codegen effects undiagnosable from source). Remaining
// *** levers (phase overlap, tile geometry, tail) all require unfreezing ->
// *** banked at this plateau. Not a HW roofline (MfmaUtil 17.5%, HBM 7%).
#define BK 64
__global__ __launch_bounds__(512, 4) void k_fgemm(const unsigned short* __restrict__ xt,
                                                  const float* __restrict__ off,
                                                  const unsigned short* __restrict__ W2,
                                                  float* __restrict__ y,
                                                  float* __restrict__ psum_s,
                                                  float* __restrict__ psum_q) {
    __shared__ __align__(16) unsigned short lA[2][256 * BK];  // 64 KB
    __shared__ __align__(16) unsigned short lB[2][64 * BK];   // 16 KB
    int t    = threadIdx.x;
    int wid  = t >> 6;
    int lane = t & 63;

    int bid  = blockIdx.x;
    int xcd  = bid & 7;
    int j    = bid >> 3;                 // 0..97
    int b    = 2 * xcd + (j >= 49 ? 1 : 0);
    int spat = (j >= 49) ? j - 49 : j;
    int n0   = spat * 64;
    const unsigned short* xb = xt + (size_t)b * HW * CH;

    int m_off = (wid >> 1) * 64;
    int n_off = (wid & 1) * 32;
    int fr = lane & 15;
    int fq = lane >> 4;

    // B-fill role: position bp (0..63), channel-group bcg (8 ch)
    int bp  = t >> 3;
    int bcg = t & 7;
    int hw = n0 + bp;
    int h = hw / 56, w = hw - h * 56;
    int lboff = bp * BK + ((bcg ^ (bp & 7)) * 8);   // swizzled LDS slot

    f32x4 acc[4][2];
#pragma unroll
    for (int m = 0; m < 4; m++)
#pragma unroll
        for (int n = 0; n < 2; n++)
            acc[m][n] = (f32x4){0.f, 0.f, 0.f, 0.f};

    int   cidx0, cidx1, cidx2, cidx3;
    float cwgt0, cwgt1, cwgt2, cwgt3;
    f32x2 wp0, wp1, wp2, wp3;
    u32x4 nv0, nv1, nv2, nv3;
    float offYn, offXn;

    // meta from (oy,ox) for tap -> corner idx/wgt (+ packed weight pairs)
#define META_COMPUTE(TAP, OY, OX)                                              \
    {                                                                          \
        float py = (float)(h + (TAP) / 3 - 1) + (OY);                          \
        float px = (float)(w + (TAP) % 3 - 1) + (OX);                          \
        float y0f = floorf(py), x0f = floorf(px);                              \
        float fy = py - y0f, fx = px - x0f;                                    \
        float wy0 = 1.f - fy, wx0 = 1.f - fx;                                  \
        float ycf0 = y0f, ycf1 = y0f + 1.f, xcf0 = x0f, xcf1 = x0f + 1.f;      \
        bool vy0 = (ycf0 >= 0.f) && (ycf0 <= 55.f);                            \
        bool vy1 = (ycf1 >= 0.f) && (ycf1 <= 55.f);                            \
        bool vx0 = (xcf0 >= 0.f) && (xcf0 <= 55.f);                            \
        bool vx1 = (xcf1 >= 0.f) && (xcf1 <= 55.f);                            \
        int yi0 = min(max((int)ycf0, 0), 55), yi1 = min(max((int)ycf1, 0), 55); \
        int xi0 = min(max((int)xcf0, 0), 55), xi1 = min(max((int)xcf1, 0), 55); \
        cidx0 = yi0 * 56 + xi0; cwgt0 = (vy0 && vx0) ? wy0 * wx0 : 0.f;        \
        cidx1 = yi0 * 56 + xi1; cwgt1 = (vy0 && vx1) ? wy0 * fx : 0.f;         \
        cidx2 = yi1 * 56 + xi0; cwgt2 = (vy1 && vx0) ? fy * wx0 : 0.f;         \
        cidx3 = yi1 * 56 + xi1; cwgt3 = (vy1 && vx1) ? fy * fx : 0.f;          \
        wp0[0] = cwgt0; wp0[1] = cwgt0;                                        \
        wp1[0] = cwgt1; wp1[1] = cwgt1;                                        \
        wp2[0] = cwgt2; wp2[1] = cwgt2;                                        \
        wp3[0] = cwgt3; wp3[1] = cwgt3;                                        \
    }

#define STAGE_A(S, BUF)                                                        \
    {                                                                          \
        _Pragma("unroll")                                                      \
        for (int i = 0; i < 4; i++) {                                          \
            int q = t + 512 * i;                                               \
            int row = q >> 3;                                                  \
            int part = (q & 7) ^ (row & 7);                                    \
            gload_lds16(W2 + (size_t)row * RDIM + (S) * 64 + part * 8,         \
                        &lA[BUF][(size_t)(wid * 64 + 512 * i) * 8]);           \
        }                                                                      \
    }

#define GATHERS(S)                                                             \
    {                                                                          \
        int c0g = ((S) & 3) * 64 + bcg * 8;                                    \
        nv0 = *(const u32x4*)(xb + (size_t)cidx0 * CH + c0g);                  \
        nv1 = *(const u32x4*)(xb + (size_t)cidx1 * CH + c0g);                  \
        nv2 = *(const u32x4*)(xb + (size_t)cidx2 * CH + c0g);                  \
        nv3 = *(const u32x4*)(xb + (size_t)cidx3 * CH + c0g);                  \
    }

// packed blend: per word i, {al,ah} pair accumulates via v_pk_mul/v_pk_fma.
// association mirrors the proven scalar chain exactly:
//   al = fma(w0,lo0, fma(w1,lo1, fma(w2,lo2, mul(w3,lo3))))   (both halves)
#define BLEND_WRITE(BUF)                                                       \
    {                                                                          \
        u32x4 ov;                                                              \
        _Pragma("unroll")                                                      \
        for (int i = 0; i < 4; i++) {                                          \
            f32x2 v0, v1, v2, v3, ac;                                          \
            v0[0] = __uint_as_float(nv0[i] << 16);                             \
            v0[1] = __uint_as_float(nv0[i] & 0xffff0000u);                     \
            v1[0] = __uint_as_float(nv1[i] << 16);                             \
            v1[1] = __uint_as_float(nv1[i] & 0xffff0000u);                     \
            v2[0] = __uint_as_float(nv2[i] << 16);                             \
            v2[1] = __uint_as_float(nv2[i] & 0xffff0000u);                     \
            v3[0] = __uint_as_float(nv3[i] << 16);                             \
            v3[1] = __uint_as_float(nv3[i] & 0xffff0000u);                     \
            ac = pkmul(wp3, v3);                                               \
            ac = pkfma(wp2, v2, ac);                                           \
            ac = pkfma(wp1, v1, ac);                                           \
            ac = pkfma(wp0, v0, ac);                                           \
            ov[i] = cvtpk(ac[0], ac[1]);                                       \
        }                                                                      \
        *(u32x4*)(&lB[BUF][lboff]) = ov;                                       \
    }

    // ---- prologue: lB[0] = B(step0); nv = gathers(step1); lA = A(step0) ----
    {
        float oy = off[(size_t)(b * 18 + 0) * HW + hw];
        float ox = off[(size_t)(b * 18 + 1) * HW + hw];
        META_COMPUTE(0, oy, ox);
    }
    GATHERS(0);
    STAGE_A(0, 0);
    offYn = off[(size_t)(b * 18 + 2) * HW + hw];
    offXn = off[(size_t)(b * 18 + 3) * HW + hw];
    BLEND_WRITE(0);
    __syncthreads();

    // ---- main loop: one barrier per K-step ----
    for (int s = 0; s < 36; ++s) {
        int cur = s & 1;
        int nxt = cur ^ 1;
        if (s < 35) {
            int s1 = s + 1;
            if ((s1 & 3) == 0) {
                int tap1 = s1 >> 2;
                META_COMPUTE(tap1, offYn, offXn);
                if (tap1 < 8) {
                    offYn = off[(size_t)(b * 18 + 2 * tap1 + 2) * HW + hw];
                    offXn = off[(size_t)(b * 18 + 2 * tap1 + 3) * HW + hw];
                }
            }
            GATHERS(s1);
            STAGE_A(s1, nxt);
        }
        // MFMA cluster on buffers[cur] (prefetch latency hides under this)
        __builtin_amdgcn_s_setprio(1);
#pragma unroll
        for (int kk = 0; kk < 2; kk++) {
            bf16x8 afr[4], bfr[2];
#pragma unroll
            for (int m = 0; m < 4; m++) {
                int row = m_off + m * 16 + fr;
                int slot = (kk * 4 + fq) ^ (row & 7);
                afr[m] = *(const bf16x8*)&lA[cur][row * BK + slot * 8];
            }
#pragma unroll
            for (int n = 0; n < 2; n++) {
                int row = n_off + n * 16 + fr;
                int slot = (kk * 4 + fq) ^ (row & 7);
                bfr[n] = *(const bf16x8*)&lB[cur][row * BK + slot * 8];
            }
#pragma unroll
            for (int m = 0; m < 4; m++)
#pragma unroll
                for (int n = 0; n < 2; n++)
                    acc[m][n] = __builtin_amdgcn_mfma_f32_16x16x32_bf16(afr[m], bfr[n], acc[m][n], 0, 0, 0);
        }
        __builtin_amdgcn_s_setprio(0);
        if (s < 35) {
            BLEND_WRITE(nxt);   // compiler inserts vmcnt for nv* before use
        }
        __syncthreads();        // drains STAGE_A vmcnt + ds_write lgkm; one barrier/step
    }

    // --- y write (pre-BN conv output) ---
    float* yb = y + (size_t)b * CH * HW;
#pragma unroll
    for (int m = 0; m < 4; m++) {
        int o = m_off + m * 16 + fq * 4;
#pragma unroll
        for (int n = 0; n < 2; n++) {
            int p = n0 + n_off + n * 16 + fr;
#pragma unroll
            for (int jj = 0; jj < 4; jj++)
                yb[(size_t)(o + jj) * HW + p] = acc[m][n][jj];
        }
    }

    // --- BN partial sums: reduce over n and fr within each fq group ---
    int blk2 = (b * 49 + spat) * 2 + (wid & 1);
#pragma unroll
    for (int m = 0; m < 4; m++)
#pragma unroll
        for (int jj = 0; jj < 4; jj++) {
            float s = acc[m][0][jj] + acc[m][1][jj];
            float q = acc[m][0][jj] * acc[m][0][jj] + acc[m][1][jj] * acc[m][1][jj];
#pragma unroll
            for (int msk = 1; msk < 16; msk <<= 1) {
                s += __shfl_xor(s, msk);
                q += __shfl_xor(q, msk);
            }
            if (fr == 0) {
                int o = m_off + m * 16 + fq * 4 + jj;
                psum_s[(size_t)o * NCOL + blk2] = s;
                psum_q[(size_t)o * NCOL + blk2] = q;
            }
        }
}

// ---------------- 4. reduce partials -> scale/shift ----------------
__global__ __launch_bounds__(256) void k_stats2(const float* __restrict__ psum_s,
                                                const float* __restrict__ psum_q,
                                                const float* __restrict__ gamma,
                                                const float* __restrict__ beta,
                                                float* __restrict__ scaleArr,
                                                float* __restrict__ shiftArr) {
    int o = blockIdx.x;
    int t = threadIdx.x;
    float s = 0.f, q = 0.f;
    for (int i = t; i < NCOL; i += 256) {
        s += psum_s[(size_t)o * NCOL + i];
        q += psum_q[(size_t)o * NCOL + i];
    }
    __shared__ float r1[256], r2[256];
    r1[t] = s; r2[t] = q;
    __syncthreads();
    for (int st = 128; st > 0; st >>= 1) {
        if (t < st) { r1[t] += r1[t + st]; r2[t] += r2[t + st]; }
        __syncthreads();
    }
    if (t == 0) {
        float inv = 1.f / (float)NPOS;
        float mean = r1[0] * inv;
        float var  = r2[0] * inv - mean * mean;
        float sc = gamma[o] * rsqrtf(var + EPSV);
        scaleArr[o] = sc;
        shiftArr[o] = beta[o] - mean * sc;
    }
}

// ---------------- 5. normalize + ReLU (in place on d_out) ----------------
__global__ __launch_bounds__(256) void k_norm(float* __restrict__ y,
                                              const float* __restrict__ scaleArr,
                                              const float* __restrict__ shiftArr) {
    const int total4 = NBAT * CH * (HW / 4);
    for (int i = blockIdx.x * 256 + threadIdx.x; i < total4; i += gridDim.x * 256) {
        int o = (i / (HW / 4)) & 255;
        float sc = scaleArr[o], sh = shiftArr[o];
        float4 v = ((const float4*)y)[i];
        float4 r;
        r.x = fmaxf(v.x * sc + sh, 0.f);
        r.y = fmaxf(v.y * sc + sh, 0.f);
        r.z = fmaxf(v.z * sc + sh, 0.f);
        r.w = fmaxf(v.w * sc + sh, 0.f);
        ((float4*)y)[i] = r;
    }
}

extern "C" void kernel_launch(void* const* d_in, const int* in_sizes, int n_in,
                              void* d_out, int out_size, void* d_ws, size_t ws_size,
                              hipStream_t stream) {
    const float* x     = (const float*)d_in[0];
    const float* off   = (const float*)d_in[1];
    const float* wgt   = (const float*)d_in[2];
    const float* gamma = (const float*)d_in[3];
    const float* beta  = (const float*)d_in[4];
    float* out = (float*)d_out;     // pre-BN conv output, normalized in place
    char* ws = (char*)d_ws;

    // workspace layout (min ~30.1 MB)
    unsigned short* W2 = (unsigned short*)(ws + 0);          //  1,179,648 B
    unsigned short* xt = (unsigned short*)(ws + 1179648);    // 25,690,112 B
    float* psum_s      = (float*)(ws + 26869760);            //  1,605,632 B
    float* psum_q      = (float*)(ws + 28475392);            //  1,605,632 B
    float* scaleArr    = (float*)(ws + 30081024);            //      1,024 B
    float* shiftArr    = (float*)(ws + 30082048);            //      1,024 B

    k_prep<<<5440, 256, 0, stream>>>(x, wgt, xt, W2);
    k_fgemm<<<784, 512, 0, stream>>>(xt, off, W2, out, psum_s, psum_q);
    k_stats2<<<256, 256, 0, stream>>>(psum_s, psum_q, gamma, beta, scaleArr, shiftArr);
    k_norm<<<2048, 256, 0, stream>>>(out, scaleArr, shiftArr);
}